// Round 3
// baseline (549.392 us; speedup 1.0000x reference)
//
#include <hip/hip_runtime.h>
#include <stddef.h>

typedef unsigned short u16;
typedef unsigned short u16x8 __attribute__((ext_vector_type(8)));
typedef short s16x8 __attribute__((ext_vector_type(8)));
typedef float f32x4 __attribute__((ext_vector_type(4)));

#define B_ 2
#define T_ 2048
#define E_ 2048
#define H_ 16

__device__ inline float us2f(u16 u){
  unsigned int i = ((unsigned int)u) << 16;
  return __builtin_bit_cast(float, i);
}
__device__ inline u16 f2us(float f){
  unsigned int x = __builtin_bit_cast(unsigned int, f);
  unsigned int r = (x + 0x7fffu + ((x >> 16) & 1u)) >> 16;
  return (u16)r;
}
__device__ inline f32x4 mfma32(s16x8 a, s16x8 b, f32x4 c){
  return __builtin_amdgcn_mfma_f32_16x16x32_bf16(a, b, c, 0, 0, 0);
}
__device__ inline s16x8 ld8(const u16* p){
  return __builtin_bit_cast(s16x8, *(const u16x8*)p);
}

// ---------------- f32 -> bf16 transpose (for weights) ----------------
__global__ void transpose_f32_bf16(const float* __restrict__ in, u16* __restrict__ out, int R, int C)
{
  __shared__ float tile[32][33];
  int c0 = blockIdx.x * 32, r0 = blockIdx.y * 32;
  int tx = threadIdx.x, ty = threadIdx.y;  // 32 x 8
  for (int i = ty; i < 32; i += 8){
    int r = r0 + i, c = c0 + tx;
    tile[i][tx] = (r < R && c < C) ? in[(size_t)r * C + c] : 0.f;
  }
  __syncthreads();
  for (int i = ty; i < 32; i += 8){
    int c = c0 + i, r = r0 + tx;
    if (c < C && r < R) out[(size_t)c * R + r] = f2us(tile[tx][i]);
  }
}

// ---------------- f32 -> bf16 flat convert (for wkv_b) ----------------
__global__ __launch_bounds__(256) void cvt_f32_bf16(const float* __restrict__ in,
    u16* __restrict__ out, int n)
{
  int i = (blockIdx.x * 256 + threadIdx.x) * 4;
  if (i + 3 < n){
    f32x4 v = *(const f32x4*)(in + i);
    out[i]   = f2us(v[0]); out[i+1] = f2us(v[1]);
    out[i+2] = f2us(v[2]); out[i+3] = f2us(v[3]);
  }
}

// ------- MFMA GEMM: C(MxN) = A(MxK) * Bt(NxK)^T; A f32-or-bf16, out f32-or-bf16 -------
template<int A_F32, int OUT_F32>
__global__ __launch_bounds__(256) void gemm_bt(const void* __restrict__ Ap,
    const u16* __restrict__ Bt, void* __restrict__ Cp, int M, int N, int K)
{
  __shared__ __align__(16) u16 As[64][40];
  __shared__ __align__(16) u16 Bs[64][40];
  const int tid  = threadIdx.x;
  const int lane = tid & 63;
  const int wid  = tid >> 6;
  const int quad = lane >> 4;
  const int col  = lane & 15;
  const int bm = blockIdx.y * 64;
  const int bn = blockIdx.x * 64;
  const int lr = tid >> 2;          // 0..63
  const int lc = (tid & 3) * 8;     // 0,8,16,24
  const int waveM = wid >> 1, waveN = wid & 1;

  f32x4 acc[2][2];
  for (int i = 0; i < 2; ++i)
    for (int j = 0; j < 2; ++j)
      acc[i][j] = (f32x4){0.f, 0.f, 0.f, 0.f};

  const u16x8 zero8 = {0,0,0,0,0,0,0,0};
  const bool bok = (bn + lr) < N;
  const u16*   arow16 = (const u16*)Ap   + (size_t)(bm + lr) * K + lc;
  const float* arow32 = (const float*)Ap + (size_t)(bm + lr) * K + lc;
  const u16* brow = Bt + (size_t)(bn + lr) * K + lc;

  for (int kk = 0; kk < K; kk += 32) {
    u16x8 av;
    if (A_F32) {
      f32x4 a0 = *(const f32x4*)(arow32 + kk);
      f32x4 a1 = *(const f32x4*)(arow32 + kk + 4);
      av[0]=f2us(a0[0]); av[1]=f2us(a0[1]); av[2]=f2us(a0[2]); av[3]=f2us(a0[3]);
      av[4]=f2us(a1[0]); av[5]=f2us(a1[1]); av[6]=f2us(a1[2]); av[7]=f2us(a1[3]);
    } else {
      av = *(const u16x8*)(arow16 + kk);
    }
    u16x8 bv = bok ? *(const u16x8*)(brow + kk) : zero8;
    __syncthreads();
    *(u16x8*)&As[lr][lc] = av;
    *(u16x8*)&Bs[lr][lc] = bv;
    __syncthreads();
    s16x8 af0 = ld8(&As[waveM*32 + col][quad*8]);
    s16x8 af1 = ld8(&As[waveM*32 + 16 + col][quad*8]);
    s16x8 bf0 = ld8(&Bs[waveN*32 + col][quad*8]);
    s16x8 bf1 = ld8(&Bs[waveN*32 + 16 + col][quad*8]);
    acc[0][0] = mfma32(af0, bf0, acc[0][0]);
    acc[0][1] = mfma32(af0, bf1, acc[0][1]);
    acc[1][0] = mfma32(af1, bf0, acc[1][0]);
    acc[1][1] = mfma32(af1, bf1, acc[1][1]);
  }
  for (int am = 0; am < 2; ++am)
    for (int bnn = 0; bnn < 2; ++bnn)
      for (int i = 0; i < 4; ++i) {
        int r = bm + waveM*32 + am*16 + quad*4 + i;
        int c = bn + waveN*32 + bnn*16 + col;
        if (c < N){
          if (OUT_F32) ((float*)Cp)[(size_t)r * N + c] = acc[am][bnn][i];
          else         ((u16*)Cp)[(size_t)r * N + c]   = f2us(acc[am][bnn][i]);
        }
      }
}

// ---------------- split q -> qh (B,H,T,96) with rope on dims 64..95 ----------
__global__ __launch_bounds__(256) void qsplit(const u16* __restrict__ qtmp,
    const int* __restrict__ pos, u16* __restrict__ qh)
{
  int idx = blockIdx.x * 256 + threadIdx.x;
  if (idx >= B_*T_*H_*48) return;
  int p   = idx % 48;
  int h   = (idx / 48) & 15;
  int row = idx / (48 * 16);       // b*T + t
  int t   = row & (T_ - 1);
  int b   = row >> 11;
  const u16* src = qtmp + (size_t)row * 1536 + h * 96;
  u16* dst = qh + ((size_t)(b * 16 + h) * T_ + t) * 96;
  int d = p * 2;
  if (d < 64) {
    dst[d] = src[d]; dst[d+1] = src[d+1];
  } else {
    int i = (d - 64) >> 1;
    float ang = (float)pos[t] * expf((float)(2*i) * -0.28782313657f); // -ln(1e4)/32
    float c = cosf(ang), s = sinf(ang);
    float xr = us2f(src[d]), xi = us2f(src[d+1]);
    dst[d]   = f2us(xr * c - xi * s);
    dst[d+1] = f2us(xr * s + xi * c);
  }
}

// --------- layernorm(kv) + P2 = kvn@fc_p_w + b + rope(k_pe), one block per row ---------
// NOTE: exactly B_*T_ = 4096 blocks. Round-2 bug: launching 8192 blocks made
// rows 4096..8191 write kvn OOB directly onto kpe/P2 (next ws buffers) -> race.
__global__ __launch_bounds__(256) void ln_p2_rope(
    const u16* __restrict__ kvall, const float* __restrict__ gamma,
    const float* __restrict__ beta, const float* __restrict__ fcpw,
    const float* __restrict__ fcpb, const int* __restrict__ pos,
    u16* __restrict__ kvn, float* __restrict__ P2, u16* __restrict__ kpe)
{
  const int row = blockIdx.x;      // b*T + t
  if (row >= B_ * T_) return;
  const int tid = threadIdx.x;
  const int lane = tid & 63, wid = tid >> 6;
  __shared__ float kvs[256];
  __shared__ float redS[4], redS2[4];
  const u16* src = kvall + (size_t)row * 288;
  float v = us2f(src[tid]);
  float s1 = v, s2 = v * v;
  for (int off = 1; off < 64; off <<= 1){
    s1 += __shfl_xor(s1, off);
    s2 += __shfl_xor(s2, off);
  }
  if (lane == 0){ redS[wid] = s1; redS2[wid] = s2; }
  __syncthreads();
  float S  = redS[0] + redS[1] + redS[2] + redS[3];
  float Q  = redS2[0] + redS2[1] + redS2[2] + redS2[3];
  float mean = S * (1.f / 256.f);
  float var  = Q * (1.f / 256.f) - mean * mean;
  float rstd = rsqrtf(var + 1e-5f);
  float xn = (v - mean) * rstd * gamma[tid] + beta[tid];
  kvs[tid] = xn;
  kvn[(size_t)row * 256 + tid] = f2us(xn);
  __syncthreads();
  if (tid < 64) {
    float acc = fcpb[tid];
    for (int c = 0; c < 256; ++c) acc += kvs[c] * fcpw[c * 64 + tid];
    P2[(size_t)row * 64 + tid] = acc;
  } else if (tid < 80) {
    int i = tid - 64;
    int t = row & (T_ - 1);
    float ang = (float)pos[t] * expf((float)(2*i) * -0.28782313657f);
    float c = cosf(ang), s = sinf(ang);
    float xr = us2f(src[256 + 2*i]);
    float xi = us2f(src[257 + 2*i]);
    kpe[(size_t)row * 32 + 2*i]     = f2us(xr * c - xi * s);
    kpe[(size_t)row * 32 + 2*i + 1] = f2us(xr * s + xi * c);
  }
}

// ---------------- C2[t] = sinusoid_pe(t/2) @ fc_c_w + b -----------------------
__global__ __launch_bounds__(64) void c2_kernel(const float* __restrict__ fccw,
    const float* __restrict__ fccb, float* __restrict__ C2)
{
  const int t = blockIdx.x, tid = threadIdx.x;
  __shared__ float pe[256];
  float p = (float)(t >> 1);
  for (int i = tid; i < 128; i += 64){
    float div = expf((float)(2*i) * -0.03597789207f);  // -ln(1e4)/256
    float a = p * div;
    pe[2*i]   = sinf(a);
    pe[2*i+1] = cosf(a);
  }
  __syncthreads();
  float acc = fccb[tid];
  for (int c = 0; c < 256; ++c) acc += pe[c] * fccw[c * 64 + tid];
  C2[t * 64 + tid] = acc;
}

// ---------------- kv_t: block-diag (DR=2) temporal conv ----------------------
// NOTE: exactly B_*T_ = 4096 blocks (same round-2 OOB bug class).
__global__ __launch_bounds__(64) void kvt_kernel(const float* __restrict__ C2,
    const float* __restrict__ P2, const u16* __restrict__ kvn, u16* __restrict__ kvt)
{
  const int row = blockIdx.x;       // b*T + t
  if (row >= B_ * T_) return;
  const int lane = threadIdx.x;
  const int t = row & (T_ - 1);
  float c2v = C2[t * 64 + lane];
  float da = c2v * P2[(size_t)row * 64 + lane];
  for (int off = 1; off < 64; off <<= 1) da += __shfl_xor(da, off);
  float wtt = 1.f / (1.f + __expf(-da));
  const bool odd = (t & 1);
  float wts = 0.f;
  if (odd){
    float db = c2v * P2[(size_t)(row - 1) * 64 + lane];
    for (int off = 1; off < 64; off <<= 1) db += __shfl_xor(db, off);
    wts = 1.f / (1.f + __expf(-db));
  }
  for (int c = lane; c < 256; c += 64){
    float val = wtt * us2f(kvn[(size_t)row * 256 + c]);
    if (odd) val += wts * us2f(kvn[(size_t)(row - 1) * 256 + c]);
    kvt[(size_t)row * 256 + c] = f2us(val);
  }
}

// ------- Vt: gather odd-position v rows from kvb and transpose -> (B,H,64,1024) -------
__global__ __launch_bounds__(256) void vt_kernel(const u16* __restrict__ kvb, u16* __restrict__ Vt)
{
  const int bid = blockIdx.x;
  const int jt = bid & 15;
  const int h  = (bid >> 4) & 15;
  const int b  = bid >> 8;
  const int tid = threadIdx.x;
  __shared__ __align__(16) u16 tile[64][72];
  const int jl = tid >> 2;
  const int dseg = (tid & 3) * 16;
  const int j0 = jt * 64;
  {
    int s_ = 2 * (j0 + jl) + 1;
    const u16* src = kvb + ((size_t)(b * T_ + s_)) * 2048 + h * 128 + 64 + dseg;
    *(u16x8*)&tile[jl][dseg]     = *(const u16x8*)(src);
    *(u16x8*)&tile[jl][dseg + 8] = *(const u16x8*)(src + 8);
  }
  __syncthreads();
  const int dl = tid >> 2;
  const int jseg = (tid & 3) * 16;
  u16* dst = Vt + ((size_t)(b * 16 + h) * 64 + dl) * 1024 + j0 + jseg;
  u16x8 o;
  for (int r = 0; r < 8; ++r) o[r] = tile[jseg + r][dl];
  *(u16x8*)dst = o;
  for (int r = 0; r < 8; ++r) o[r] = tile[jseg + 8 + r][dl];
  *(u16x8*)(dst + 8) = o;
}

// ---------------- flash attention over compressed (odd) keys + self ----------
__global__ __launch_bounds__(256) void attn_kernel(
    const u16* __restrict__ qh, const u16* __restrict__ kvb,
    const u16* __restrict__ kpe, const u16* __restrict__ Vt,
    u16* __restrict__ xout)
{
  __shared__ __align__(16) u16 pbuf_all[4][512];   // per-wave 16x32 P tile
  const int tid  = threadIdx.x;
  const int wid  = tid >> 6;
  const int lane = tid & 63;
  const int quad = lane >> 4;
  const int col  = lane & 15;
  const int bidx = blockIdx.x;
  const int qt = bidx & 31;
  const int h  = (bidx >> 5) & 15;
  const int b  = bidx >> 9;
  const int t0 = qt * 64 + wid * 16;
  const int bh = b * H_ + h;
  u16* pbuf = pbuf_all[wid];
  const float scale = 0.10206207262f;   // 96^-0.5

  // Q fragments (A-operand): 16 queries x 96 dims
  s16x8 aq0, aq1, aq2;
  {
    const int t = t0 + col;
    const u16* qrow = qh + ((size_t)bh * T_ + t) * 96;
    aq0 = ld8(qrow + quad * 8);
    aq1 = ld8(qrow + 32 + quad * 8);
    aq2 = ld8(qrow + 64 + quad * 8);
  }
  // self score (lanes with col==r compute row r's self score)
  float sself;
  {
    const int t = t0 + col;
    const u16* qrow = qh + ((size_t)bh * T_ + t) * 96;
    const u16* ka = kvb + ((size_t)(b * T_ + t)) * 2048 + h * 128;
    const u16* kp = kpe + ((size_t)(b * T_ + t)) * 32;
    float a = 0.f;
    for (int d = 0; d < 64; ++d) a += us2f(qrow[d]) * us2f(ka[d]);
    for (int d = 0; d < 32; ++d) a += us2f(qrow[64 + d]) * us2f(kp[d]);
    sself = a * scale;
  }
  float m_i[4], l_i[4];
  f32x4 O[4];
  for (int i = 0; i < 4; ++i){ m_i[i] = __shfl(sself, quad * 4 + i); l_i[i] = 1.f; }
  for (int nt = 0; nt < 4; ++nt)
    for (int i = 0; i < 4; ++i){
      int t = t0 + quad * 4 + i;
      O[nt][i] = us2f(kvb[((size_t)(b * T_ + t)) * 2048 + h * 128 + 64 + nt * 16 + col]);
    }

  const int jmaxcnt = (t0 + 15) >> 1;          // max #compressed keys over rows
  const int nb = (jmaxcnt + 31) >> 5;
  for (int blk = 0; blk < nb; ++blk) {
    const int jb = blk * 32;
    f32x4 s0 = {0,0,0,0}, s1 = {0,0,0,0};
    {
      int s_ = 2 * (jb + col) + 1;
      const u16* ka = kvb + ((size_t)(b * T_ + s_)) * 2048 + h * 128;
      const u16* kp = kpe + ((size_t)(b * T_ + s_)) * 32;
      s0 = mfma32(aq0, ld8(ka + quad * 8), s0);
      s0 = mfma32(aq1, ld8(ka + 32 + quad * 8), s0);
      s0 = mfma32(aq2, ld8(kp + quad * 8), s0);
    }
    {
      int s_ = 2 * (jb + 16 + col) + 1;
      const u16* ka = kvb + ((size_t)(b * T_ + s_)) * 2048 + h * 128;
      const u16* kp = kpe + ((size_t)(b * T_ + s_)) * 32;
      s1 = mfma32(aq0, ld8(ka + quad * 8), s1);
      s1 = mfma32(aq1, ld8(ka + 32 + quad * 8), s1);
      s1 = mfma32(aq2, ld8(kp + quad * 8), s1);
    }
    float p0[4], p1[4], alpha[4];
    for (int i = 0; i < 4; ++i){
      int t = t0 + quad * 4 + i;
      int lim = t >> 1;
      float v0 = (jb + col < lim)      ? s0[i] * scale : -1e30f;
      float v1 = (jb + 16 + col < lim) ? s1[i] * scale : -1e30f;
      float mx = fmaxf(v0, v1);
      mx = fmaxf(mx, __shfl_xor(mx, 1));
      mx = fmaxf(mx, __shfl_xor(mx, 2));
      mx = fmaxf(mx, __shfl_xor(mx, 4));
      mx = fmaxf(mx, __shfl_xor(mx, 8));
      float mn = fmaxf(m_i[i], mx);
      alpha[i] = __expf(m_i[i] - mn);
      float e0 = __expf(v0 - mn);
      float e1 = __expf(v1 - mn);
      p0[i] = e0; p1[i] = e1;
      float ps = e0 + e1;
      ps += __shfl_xor(ps, 1);
      ps += __shfl_xor(ps, 2);
      ps += __shfl_xor(ps, 4);
      ps += __shfl_xor(ps, 8);
      l_i[i] = l_i[i] * alpha[i] + ps;
      m_i[i] = mn;
    }
    for (int nt = 0; nt < 4; ++nt)
      for (int i = 0; i < 4; ++i) O[nt][i] *= alpha[i];
    for (int i = 0; i < 4; ++i){
      pbuf[(quad * 4 + i) * 32 + col]      = f2us(p0[i]);
      pbuf[(quad * 4 + i) * 32 + 16 + col] = f2us(p1[i]);
    }
    asm volatile("s_waitcnt lgkmcnt(0)" ::: "memory");
    s16x8 pf = ld8(&pbuf[col * 32 + quad * 8]);
    for (int nt = 0; nt < 4; ++nt){
      const u16* vr = Vt + ((size_t)bh * 64 + nt * 16 + col) * 1024 + jb + quad * 8;
      O[nt] = mfma32(pf, ld8(vr), O[nt]);
    }
  }
  for (int nt = 0; nt < 4; ++nt)
    for (int i = 0; i < 4; ++i){
      int t = t0 + quad * 4 + i;
      xout[((size_t)(b * T_ + t)) * 1024 + h * 64 + nt * 16 + col] = f2us(O[nt][i] / l_i[i]);
    }
}

extern "C" void kernel_launch(void* const* d_in, const int* in_sizes, int n_in,
                              void* d_out, int out_size, void* d_ws, size_t ws_size,
                              hipStream_t stream)
{
  (void)in_sizes; (void)n_in; (void)out_size; (void)ws_size;
  const float* query = (const float*)d_in[0];
  const float* key_  = (const float*)d_in[1];
  const int*   pos   = (const int*)d_in[3];
  const float* wq    = (const float*)d_in[4];
  const float* wkva  = (const float*)d_in[5];
  const float* gamma = (const float*)d_in[6];
  const float* beta  = (const float*)d_in[7];
  const float* wkvb  = (const float*)d_in[8];
  const float* wo    = (const float*)d_in[9];
  const float* fccw  = (const float*)d_in[10];
  const float* fccb  = (const float*)d_in[11];
  const float* fcpw  = (const float*)d_in[12];
  const float* fcpb  = (const float*)d_in[13];

  char* p = (char*)d_ws;
  auto alloc = [&](size_t bytes) -> void* {
    void* r = (void*)p;
    p += (bytes + 255) & ~(size_t)255;
    return r;
  };
  u16* wqT   = (u16*)alloc(1536ull * 2048 * 2);
  u16* wkvaT = (u16*)alloc(288ull  * 2048 * 2);
  u16* woT   = (u16*)alloc(2048ull * 1024 * 2);
  u16* wkvbB = (u16*)alloc(2048ull * 256 * 2);
  u16* qtmp  = (u16*)alloc(4096ull * 1536 * 2);
  u16* qh    = (u16*)alloc(65536ull * 96 * 2);     // (B,H,T,96)
  u16* kvall = (u16*)alloc(4096ull * 288 * 2);
  u16* kvn   = (u16*)alloc(4096ull * 256 * 2);
  u16* kpe   = (u16*)alloc(4096ull * 32 * 2);
  float* P2  = (float*)alloc(4096ull * 64 * 4);
  float* C2  = (float*)alloc(2048ull * 64 * 4);
  u16* kvt   = (u16*)alloc(4096ull * 256 * 2);
  u16* kvb   = (u16*)alloc(4096ull * 2048 * 2);    // per-head [k_abs(64) | v(64)]
  u16* Vt    = (u16*)alloc(2048ull * 1024 * 2);    // (B,H,64,1024) transposed compressed V
  u16* x     = (u16*)alloc(4096ull * 1024 * 2);

  dim3 tb(32, 8);
  transpose_f32_bf16<<<dim3(48, 64), tb, 0, stream>>>(wq,   wqT,   2048, 1536);
  transpose_f32_bf16<<<dim3(9,  64), tb, 0, stream>>>(wkva, wkvaT, 2048, 288);
  transpose_f32_bf16<<<dim3(64, 32), tb, 0, stream>>>(wo,   woT,   1024, 2048);
  cvt_f32_bf16<<<512, 256, 0, stream>>>(wkvb, wkvbB, 2048 * 256);

  gemm_bt<1,0><<<dim3(24, 64), 256, 0, stream>>>(query, wqT,   qtmp,  4096, 1536, 2048);
  gemm_bt<1,0><<<dim3(5,  64), 256, 0, stream>>>(key_,  wkvaT, kvall, 4096, 288,  2048);

  qsplit<<<12288, 256, 0, stream>>>(qtmp, pos, qh);
  ln_p2_rope<<<4096, 256, 0, stream>>>(kvall, gamma, beta, fcpw, fcpb, pos, kvn, P2, kpe);
  c2_kernel<<<2048, 64, 0, stream>>>(fccw, fccb, C2);
  kvt_kernel<<<4096, 64, 0, stream>>>(C2, P2, kvn, kvt);

  gemm_bt<0,0><<<dim3(32, 64), 256, 0, stream>>>(kvt, wkvbB, kvb, 4096, 2048, 256);
  vt_kernel<<<512, 256, 0, stream>>>(kvb, Vt);
  attn_kernel<<<1024, 256, 0, stream>>>(qh, kvb, kpe, Vt, x);

  gemm_bt<0,1><<<dim3(32, 64), 256, 0, stream>>>(x, woT, d_out, 4096, 2048, 1024);
}

// Round 4
// 443.197 us; speedup vs baseline: 1.2396x; 1.2396x over previous
//
#include <hip/hip_runtime.h>
#include <stddef.h>

typedef unsigned short u16;
typedef unsigned short u16x8 __attribute__((ext_vector_type(8)));
typedef short s16x8 __attribute__((ext_vector_type(8)));
typedef float f32x4 __attribute__((ext_vector_type(4)));

#define B_ 2
#define T_ 2048
#define E_ 2048
#define H_ 16

__device__ inline float us2f(u16 u){
  unsigned int i = ((unsigned int)u) << 16;
  return __builtin_bit_cast(float, i);
}
__device__ inline u16 f2us(float f){
  unsigned int x = __builtin_bit_cast(unsigned int, f);
  unsigned int r = (x + 0x7fffu + ((x >> 16) & 1u)) >> 16;
  return (u16)r;
}
__device__ inline f32x4 mfma32(s16x8 a, s16x8 b, f32x4 c){
  return __builtin_amdgcn_mfma_f32_16x16x32_bf16(a, b, c, 0, 0, 0);
}
__device__ inline s16x8 ld8(const u16* p){
  return __builtin_bit_cast(s16x8, *(const u16x8*)p);
}
// async global->LDS, 16B per lane; LDS dest = wave-uniform base + lane*16 (m97/m104)
__device__ inline void gload_lds16(const u16* g, u16* l){
  __builtin_amdgcn_global_load_lds(
      (const __attribute__((address_space(1))) unsigned int*)(g),
      (__attribute__((address_space(3))) unsigned int*)(l), 16, 0, 0);
}

// ---------------- f32 -> bf16 transpose (for weights) ----------------
__global__ void transpose_f32_bf16(const float* __restrict__ in, u16* __restrict__ out, int R, int C)
{
  __shared__ float tile[32][33];
  int c0 = blockIdx.x * 32, r0 = blockIdx.y * 32;
  int tx = threadIdx.x, ty = threadIdx.y;  // 32 x 8
  for (int i = ty; i < 32; i += 8){
    int r = r0 + i, c = c0 + tx;
    tile[i][tx] = (r < R && c < C) ? in[(size_t)r * C + c] : 0.f;
  }
  __syncthreads();
  for (int i = ty; i < 32; i += 8){
    int c = c0 + i, r = r0 + tx;
    if (c < C && r < R) out[(size_t)c * R + r] = f2us(tile[tx][i]);
  }
}

// ---------------- f32 -> bf16 flat convert ----------------
__global__ __launch_bounds__(256) void cvt_f32_bf16(const float* __restrict__ in,
    u16* __restrict__ out, int n)
{
  int i = (blockIdx.x * 256 + threadIdx.x) * 4;
  if (i + 3 < n){
    f32x4 v = *(const f32x4*)(in + i);
    out[i]   = f2us(v[0]); out[i+1] = f2us(v[1]);
    out[i+2] = f2us(v[2]); out[i+3] = f2us(v[3]);
  }
}

// ------- legacy 64x64 MFMA GEMM (for N=288 kvall only): C = A * Bt^T -------
template<int A_F32, int OUT_F32>
__global__ __launch_bounds__(256) void gemm_bt(const void* __restrict__ Ap,
    const u16* __restrict__ Bt, void* __restrict__ Cp, int M, int N, int K)
{
  __shared__ __align__(16) u16 As[64][40];
  __shared__ __align__(16) u16 Bs[64][40];
  const int tid  = threadIdx.x;
  const int lane = tid & 63;
  const int wid  = tid >> 6;
  const int quad = lane >> 4;
  const int col  = lane & 15;
  const int bm = blockIdx.y * 64;
  const int bn = blockIdx.x * 64;
  const int lr = tid >> 2;
  const int lc = (tid & 3) * 8;
  const int waveM = wid >> 1, waveN = wid & 1;

  f32x4 acc[2][2];
  for (int i = 0; i < 2; ++i)
    for (int j = 0; j < 2; ++j)
      acc[i][j] = (f32x4){0.f, 0.f, 0.f, 0.f};

  const u16x8 zero8 = {0,0,0,0,0,0,0,0};
  const bool bok = (bn + lr) < N;
  const u16*   arow16 = (const u16*)Ap   + (size_t)(bm + lr) * K + lc;
  const float* arow32 = (const float*)Ap + (size_t)(bm + lr) * K + lc;
  const u16* brow = Bt + (size_t)(bn + lr) * K + lc;

  for (int kk = 0; kk < K; kk += 32) {
    u16x8 av;
    if (A_F32) {
      f32x4 a0 = *(const f32x4*)(arow32 + kk);
      f32x4 a1 = *(const f32x4*)(arow32 + kk + 4);
      av[0]=f2us(a0[0]); av[1]=f2us(a0[1]); av[2]=f2us(a0[2]); av[3]=f2us(a0[3]);
      av[4]=f2us(a1[0]); av[5]=f2us(a1[1]); av[6]=f2us(a1[2]); av[7]=f2us(a1[3]);
    } else {
      av = *(const u16x8*)(arow16 + kk);
    }
    u16x8 bv = bok ? *(const u16x8*)(brow + kk) : zero8;
    __syncthreads();
    *(u16x8*)&As[lr][lc] = av;
    *(u16x8*)&Bs[lr][lc] = bv;
    __syncthreads();
    s16x8 af0 = ld8(&As[waveM*32 + col][quad*8]);
    s16x8 af1 = ld8(&As[waveM*32 + 16 + col][quad*8]);
    s16x8 bf0 = ld8(&Bs[waveN*32 + col][quad*8]);
    s16x8 bf1 = ld8(&Bs[waveN*32 + 16 + col][quad*8]);
    acc[0][0] = mfma32(af0, bf0, acc[0][0]);
    acc[0][1] = mfma32(af0, bf1, acc[0][1]);
    acc[1][0] = mfma32(af1, bf0, acc[1][0]);
    acc[1][1] = mfma32(af1, bf1, acc[1][1]);
  }
  for (int am = 0; am < 2; ++am)
    for (int bnn = 0; bnn < 2; ++bnn)
      for (int i = 0; i < 4; ++i) {
        int r = bm + waveM*32 + am*16 + quad*4 + i;
        int c = bn + waveN*32 + bnn*16 + col;
        if (c < N){
          if (OUT_F32) ((float*)Cp)[(size_t)r * N + c] = acc[am][bnn][i];
          else         ((u16*)Cp)[(size_t)r * N + c]   = f2us(acc[am][bnn][i]);
        }
      }
}

// ------- m97-style 128x128 GEMM: C(MxN) = A(MxK) * Bt(NxK)^T, bf16 in -------
// Requires M%128==0, N%128==0, K%32==0.
template<int OUT_F32>
__global__ __launch_bounds__(256) void gemm128(const u16* __restrict__ A,
    const u16* __restrict__ Bt, void* __restrict__ Cp, int M, int N, int K)
{
  __shared__ __align__(16) u16 As[128 * 32];
  __shared__ __align__(16) u16 Bs[128 * 32];
  const int tid  = threadIdx.x;
  const int lane = tid & 63;
  const int wid  = tid >> 6;
  const int quad = lane >> 4;
  const int col  = lane & 15;
  const int bm = blockIdx.y * 128;
  const int bn = blockIdx.x * 128;
  const int waveM = wid >> 1, waveN = wid & 1;

  // staging: instr i in {0,1}: global row = wid*16 + (lane>>2) + i*64, chunk (lane&3)*8
  const int srow = wid * 16 + (lane >> 2);
  const int scol = (lane & 3) * 8;
  const u16* ga = A  + (size_t)(bm + srow) * K + scol;
  const u16* gb = Bt + (size_t)(bn + srow) * K + scol;
  const size_t rowskip = (size_t)64 * K;
  u16* lAs0 = &As[wid * 512];
  u16* lAs1 = &As[wid * 512 + 2048];
  u16* lBs0 = &Bs[wid * 512];
  u16* lBs1 = &Bs[wid * 512 + 2048];

  f32x4 acc[4][4] = {};

  for (int kk = 0; kk < K; kk += 32) {
    __syncthreads();
    gload_lds16(ga + kk,           lAs0);
    gload_lds16(ga + rowskip + kk, lAs1);
    gload_lds16(gb + kk,           lBs0);
    gload_lds16(gb + rowskip + kk, lBs1);
    __syncthreads();
    s16x8 af[4], bf[4];
#pragma unroll
    for (int i = 0; i < 4; ++i) af[i] = ld8(&As[(waveM*64 + i*16 + col) * 32 + quad*8]);
#pragma unroll
    for (int i = 0; i < 4; ++i) bf[i] = ld8(&Bs[(waveN*64 + i*16 + col) * 32 + quad*8]);
#pragma unroll
    for (int i = 0; i < 4; ++i)
#pragma unroll
      for (int j = 0; j < 4; ++j)
        acc[i][j] = mfma32(af[i], bf[j], acc[i][j]);
  }
#pragma unroll
  for (int i = 0; i < 4; ++i)
#pragma unroll
    for (int j = 0; j < 4; ++j)
#pragma unroll
      for (int r = 0; r < 4; ++r) {
        int row = bm + waveM*64 + i*16 + quad*4 + r;
        int c   = bn + waveN*64 + j*16 + col;
        if (OUT_F32) ((float*)Cp)[(size_t)row * N + c] = acc[i][j][r];
        else         ((u16*)Cp)[(size_t)row * N + c]   = f2us(acc[i][j][r]);
      }
}

// ---------------- split q -> qh (B,H,T,96) with rope on dims 64..95 ----------
__global__ __launch_bounds__(256) void qsplit(const u16* __restrict__ qtmp,
    const int* __restrict__ pos, u16* __restrict__ qh)
{
  int idx = blockIdx.x * 256 + threadIdx.x;
  if (idx >= B_*T_*H_*48) return;
  int p   = idx % 48;
  int h   = (idx / 48) & 15;
  int row = idx / (48 * 16);       // b*T + t
  int t   = row & (T_ - 1);
  int b   = row >> 11;
  const u16* src = qtmp + (size_t)row * 1536 + h * 96;
  u16* dst = qh + ((size_t)(b * 16 + h) * T_ + t) * 96;
  int d = p * 2;
  if (d < 64) {
    dst[d] = src[d]; dst[d+1] = src[d+1];
  } else {
    int i = (d - 64) >> 1;
    float ang = (float)pos[t] * expf((float)(2*i) * -0.28782313657f); // -ln(1e4)/32
    float c = cosf(ang), s = sinf(ang);
    float xr = us2f(src[d]), xi = us2f(src[d+1]);
    dst[d]   = f2us(xr * c - xi * s);
    dst[d+1] = f2us(xr * s + xi * c);
  }
}

// --------- layernorm(kv) + P2 + rope(k_pe); exactly B_*T_ blocks ---------
__global__ __launch_bounds__(256) void ln_p2_rope(
    const u16* __restrict__ kvall, const float* __restrict__ gamma,
    const float* __restrict__ beta, const float* __restrict__ fcpw,
    const float* __restrict__ fcpb, const int* __restrict__ pos,
    u16* __restrict__ kvn, float* __restrict__ P2, u16* __restrict__ kpe)
{
  const int row = blockIdx.x;      // b*T + t
  if (row >= B_ * T_) return;
  const int tid = threadIdx.x;
  const int lane = tid & 63, wid = tid >> 6;
  __shared__ float kvs[256];
  __shared__ float redS[4], redS2[4];
  const u16* src = kvall + (size_t)row * 288;
  float v = us2f(src[tid]);
  float s1 = v, s2 = v * v;
  for (int off = 1; off < 64; off <<= 1){
    s1 += __shfl_xor(s1, off);
    s2 += __shfl_xor(s2, off);
  }
  if (lane == 0){ redS[wid] = s1; redS2[wid] = s2; }
  __syncthreads();
  float S  = redS[0] + redS[1] + redS[2] + redS[3];
  float Q  = redS2[0] + redS2[1] + redS2[2] + redS2[3];
  float mean = S * (1.f / 256.f);
  float var  = Q * (1.f / 256.f) - mean * mean;
  float rstd = rsqrtf(var + 1e-5f);
  float xn = (v - mean) * rstd * gamma[tid] + beta[tid];
  kvs[tid] = xn;
  kvn[(size_t)row * 256 + tid] = f2us(xn);
  __syncthreads();
  if (tid < 64) {
    float acc = fcpb[tid];
    for (int c = 0; c < 256; ++c) acc += kvs[c] * fcpw[c * 64 + tid];
    P2[(size_t)row * 64 + tid] = acc;
  } else if (tid < 80) {
    int i = tid - 64;
    int t = row & (T_ - 1);
    float ang = (float)pos[t] * expf((float)(2*i) * -0.28782313657f);
    float c = cosf(ang), s = sinf(ang);
    float xr = us2f(src[256 + 2*i]);
    float xi = us2f(src[257 + 2*i]);
    kpe[(size_t)row * 32 + 2*i]     = f2us(xr * c - xi * s);
    kpe[(size_t)row * 32 + 2*i + 1] = f2us(xr * s + xi * c);
  }
}

// ---------------- C2[t] = sinusoid_pe(t/2) @ fc_c_w + b -----------------------
__global__ __launch_bounds__(64) void c2_kernel(const float* __restrict__ fccw,
    const float* __restrict__ fccb, float* __restrict__ C2)
{
  const int t = blockIdx.x, tid = threadIdx.x;
  __shared__ float pe[256];
  float p = (float)(t >> 1);
  for (int i = tid; i < 128; i += 64){
    float div = expf((float)(2*i) * -0.03597789207f);  // -ln(1e4)/256
    float a = p * div;
    pe[2*i]   = sinf(a);
    pe[2*i+1] = cosf(a);
  }
  __syncthreads();
  float acc = fccb[tid];
  for (int c = 0; c < 256; ++c) acc += pe[c] * fccw[c * 64 + tid];
  C2[t * 64 + tid] = acc;
}

// ---------------- kv_t: block-diag (DR=2) temporal conv; B_*T_ blocks --------
__global__ __launch_bounds__(64) void kvt_kernel(const float* __restrict__ C2,
    const float* __restrict__ P2, const u16* __restrict__ kvn, u16* __restrict__ kvt)
{
  const int row = blockIdx.x;       // b*T + t
  if (row >= B_ * T_) return;
  const int lane = threadIdx.x;
  const int t = row & (T_ - 1);
  float c2v = C2[t * 64 + lane];
  float da = c2v * P2[(size_t)row * 64 + lane];
  for (int off = 1; off < 64; off <<= 1) da += __shfl_xor(da, off);
  float wtt = 1.f / (1.f + __expf(-da));
  const bool odd = (t & 1);
  float wts = 0.f;
  if (odd){
    float db = c2v * P2[(size_t)(row - 1) * 64 + lane];
    for (int off = 1; off < 64; off <<= 1) db += __shfl_xor(db, off);
    wts = 1.f / (1.f + __expf(-db));
  }
  for (int c = lane; c < 256; c += 64){
    float val = wtt * us2f(kvn[(size_t)row * 256 + c]);
    if (odd) val += wts * us2f(kvn[(size_t)(row - 1) * 256 + c]);
    kvt[(size_t)row * 256 + c] = f2us(val);
  }
}

// ------- Vt: gather odd-position v rows from kvb, transpose -> (B,H,64,1024) -------
__global__ __launch_bounds__(256) void vt_kernel(const u16* __restrict__ kvb, u16* __restrict__ Vt)
{
  const int bid = blockIdx.x;
  const int jt = bid & 15;
  const int h  = (bid >> 4) & 15;
  const int b  = bid >> 8;
  const int tid = threadIdx.x;
  __shared__ __align__(16) u16 tile[64][72];
  const int jl = tid >> 2;
  const int dseg = (tid & 3) * 16;
  const int j0 = jt * 64;
  {
    int s_ = 2 * (j0 + jl) + 1;
    const u16* src = kvb + ((size_t)(b * T_ + s_)) * 2048 + h * 128 + 64 + dseg;
    *(u16x8*)&tile[jl][dseg]     = *(const u16x8*)(src);
    *(u16x8*)&tile[jl][dseg + 8] = *(const u16x8*)(src + 8);
  }
  __syncthreads();
  const int dl = tid >> 2;
  const int jseg = (tid & 3) * 16;
  u16* dst = Vt + ((size_t)(b * 16 + h) * 64 + dl) * 1024 + j0 + jseg;
  u16x8 o;
  for (int r = 0; r < 8; ++r) o[r] = tile[jseg + r][dl];
  *(u16x8*)dst = o;
  for (int r = 0; r < 8; ++r) o[r] = tile[jseg + 8 + r][dl];
  *(u16x8*)(dst + 8) = o;
}

// ------- Kc: gather compressed keys -> (B,H,1024,96) = [k_abs(64)|kpe(32)] -------
__global__ __launch_bounds__(256) void kc_gather(const u16* __restrict__ kvb,
    const u16* __restrict__ kpe, u16* __restrict__ Kc)
{
  int idx = blockIdx.x * 256 + threadIdx.x;    // chunk of 8 elems
  // total chunks = B*H*1024*12 = 393216
  int c  = idx % 12;
  int j  = (idx / 12) & 1023;
  int bh = idx / (12 * 1024);
  if (bh >= B_ * H_) return;
  int b = bh >> 4, h = bh & 15;
  int t = 2 * j + 1;
  u16x8 v;
  if (c < 8) v = *(const u16x8*)(kvb + ((size_t)(b * T_ + t)) * 2048 + h * 128 + c * 8);
  else       v = *(const u16x8*)(kpe + ((size_t)(b * T_ + t)) * 32 + (c - 8) * 8);
  *(u16x8*)(Kc + ((size_t)bh * 1024 + j) * 96 + c * 8) = v;
}

// ---------------- flash attention, LDS-staged K/V, paired q-tiles ----------
__global__ __launch_bounds__(256) void attn_kernel(
    const u16* __restrict__ qh, const u16* __restrict__ kvb,
    const u16* __restrict__ kpe, const u16* __restrict__ Kc,
    const u16* __restrict__ Vt, u16* __restrict__ xout)
{
  __shared__ __align__(16) u16 Ks[32][104];      // 32 keys x [k_abs|kpe], padded
  __shared__ __align__(16) u16 Vs[64][40];       // 64 dims x 32 keys, padded
  __shared__ __align__(16) u16 pbuf_all[4][512]; // per-wave 16x32 P tile
  const int tid  = threadIdx.x;
  const int wid  = tid >> 6;
  const int lane = tid & 63;
  const int quad = lane >> 4;
  const int col  = lane & 15;
  const int pair = blockIdx.x & 15;
  const int h    = (blockIdx.x >> 4) & 15;
  const int b    = blockIdx.x >> 8;
  const int bh   = b * H_ + h;
  u16* pbuf = pbuf_all[wid];
  const float scale = 0.10206207262f;   // 96^-0.5
  const u16* KcH = Kc + (size_t)bh * 1024 * 96;
  const u16* VtH = Vt + (size_t)bh * 64 * 1024;

  for (int ph = 0; ph < 2; ++ph) {
    const int qt = ph ? (31 - pair) : pair;      // balanced: nb_a+nb_b ~ const
    const int t0 = qt * 64 + wid * 16;

    s16x8 aq0, aq1, aq2;
    {
      const u16* qrow = qh + ((size_t)bh * T_ + t0 + col) * 96;
      aq0 = ld8(qrow + quad * 8);
      aq1 = ld8(qrow + 32 + quad * 8);
      aq2 = ld8(qrow + 64 + quad * 8);
    }
    float sself;
    {
      const int t = t0 + col;
      const u16* qrow = qh + ((size_t)bh * T_ + t) * 96;
      const u16* ka = kvb + ((size_t)(b * T_ + t)) * 2048 + h * 128;
      const u16* kp = kpe + ((size_t)(b * T_ + t)) * 32;
      float a = 0.f;
      for (int d = 0; d < 64; ++d) a += us2f(qrow[d]) * us2f(ka[d]);
      for (int d = 0; d < 32; ++d) a += us2f(qrow[64 + d]) * us2f(kp[d]);
      sself = a * scale;
    }
    float m_i[4], l_i[4];
    f32x4 O[4];
    for (int i = 0; i < 4; ++i){ m_i[i] = __shfl(sself, quad * 4 + i); l_i[i] = 1.f; }
    for (int nt = 0; nt < 4; ++nt)
      for (int i = 0; i < 4; ++i){
        int t = t0 + quad * 4 + i;
        O[nt][i] = us2f(kvb[((size_t)(b * T_ + t)) * 2048 + h * 128 + 64 + nt * 16 + col]);
      }

    const int nb = (((qt * 64 + 48 + 15) >> 1) + 31) >> 5;   // block-uniform
    for (int blk = 0; blk < nb; ++blk) {
      const int jb = blk * 32;
      __syncthreads();
      {
        // stage K: 32 rows x 64 (k_abs) via 256 thr, + 32 rows x 32 (kpe) via 128 thr
        int r = tid >> 3, c = tid & 7;
        *(u16x8*)&Ks[r][c * 8] = *(const u16x8*)(KcH + (size_t)(jb + r) * 96 + c * 8);
        if (tid < 128){
          int r2 = tid >> 2, c2 = tid & 3;
          *(u16x8*)&Ks[r2][64 + c2 * 8] = *(const u16x8*)(KcH + (size_t)(jb + r2) * 96 + 64 + c2 * 8);
        }
        int vr = tid >> 2, vc = tid & 3;
        *(u16x8*)&Vs[vr][vc * 8] = *(const u16x8*)(VtH + (size_t)vr * 1024 + jb + vc * 8);
      }
      __syncthreads();
      f32x4 s0 = {0,0,0,0}, s1 = {0,0,0,0};
      s0 = mfma32(aq0, ld8(&Ks[col][quad * 8]), s0);
      s0 = mfma32(aq1, ld8(&Ks[col][32 + quad * 8]), s0);
      s0 = mfma32(aq2, ld8(&Ks[col][64 + quad * 8]), s0);
      s1 = mfma32(aq0, ld8(&Ks[16 + col][quad * 8]), s1);
      s1 = mfma32(aq1, ld8(&Ks[16 + col][32 + quad * 8]), s1);
      s1 = mfma32(aq2, ld8(&Ks[16 + col][64 + quad * 8]), s1);

      float p0[4], p1[4], alpha[4];
      for (int i = 0; i < 4; ++i){
        int t = t0 + quad * 4 + i;
        int lim = t >> 1;
        float v0 = (jb + col < lim)      ? s0[i] * scale : -1e30f;
        float v1 = (jb + 16 + col < lim) ? s1[i] * scale : -1e30f;
        float mx = fmaxf(v0, v1);
        mx = fmaxf(mx, __shfl_xor(mx, 1));
        mx = fmaxf(mx, __shfl_xor(mx, 2));
        mx = fmaxf(mx, __shfl_xor(mx, 4));
        mx = fmaxf(mx, __shfl_xor(mx, 8));
        float mn = fmaxf(m_i[i], mx);
        alpha[i] = __expf(m_i[i] - mn);
        float e0 = __expf(v0 - mn);
        float e1 = __expf(v1 - mn);
        p0[i] = e0; p1[i] = e1;
        float ps = e0 + e1;
        ps += __shfl_xor(ps, 1);
        ps += __shfl_xor(ps, 2);
        ps += __shfl_xor(ps, 4);
        ps += __shfl_xor(ps, 8);
        l_i[i] = l_i[i] * alpha[i] + ps;
        m_i[i] = mn;
      }
      for (int nt = 0; nt < 4; ++nt)
        for (int i = 0; i < 4; ++i) O[nt][i] *= alpha[i];
      for (int i = 0; i < 4; ++i){
        pbuf[(quad * 4 + i) * 32 + col]      = f2us(p0[i]);
        pbuf[(quad * 4 + i) * 32 + 16 + col] = f2us(p1[i]);
      }
      asm volatile("s_waitcnt lgkmcnt(0)" ::: "memory");
      s16x8 pf = ld8(&pbuf[col * 32 + quad * 8]);
      for (int nt = 0; nt < 4; ++nt)
        O[nt] = mfma32(pf, ld8(&Vs[nt * 16 + col][quad * 8]), O[nt]);
    }
    for (int nt = 0; nt < 4; ++nt)
      for (int i = 0; i < 4; ++i){
        int t = t0 + quad * 4 + i;
        xout[((size_t)(b * T_ + t)) * 1024 + h * 64 + nt * 16 + col] = f2us(O[nt][i] / l_i[i]);
      }
    __syncthreads();   // protect Ks/Vs before next phase restages
  }
}

extern "C" void kernel_launch(void* const* d_in, const int* in_sizes, int n_in,
                              void* d_out, int out_size, void* d_ws, size_t ws_size,
                              hipStream_t stream)
{
  (void)in_sizes; (void)n_in; (void)out_size; (void)ws_size;
  const float* query = (const float*)d_in[0];
  const float* key_  = (const float*)d_in[1];
  const int*   pos   = (const int*)d_in[3];
  const float* wq    = (const float*)d_in[4];
  const float* wkva  = (const float*)d_in[5];
  const float* gamma = (const float*)d_in[6];
  const float* beta  = (const float*)d_in[7];
  const float* wkvb  = (const float*)d_in[8];
  const float* wo    = (const float*)d_in[9];
  const float* fccw  = (const float*)d_in[10];
  const float* fccb  = (const float*)d_in[11];
  const float* fcpw  = (const float*)d_in[12];
  const float* fcpb  = (const float*)d_in[13];

  char* p = (char*)d_ws;
  auto alloc = [&](size_t bytes) -> void* {
    void* r = (void*)p;
    p += (bytes + 255) & ~(size_t)255;
    return r;
  };
  u16* wqT    = (u16*)alloc(1536ull * 2048 * 2);
  u16* wkvaT  = (u16*)alloc(288ull  * 2048 * 2);
  u16* woT    = (u16*)alloc(2048ull * 1024 * 2);
  u16* wkvbB  = (u16*)alloc(2048ull * 256 * 2);
  u16* queryB = (u16*)alloc(4096ull * 2048 * 2);
  u16* keyB   = (u16*)alloc(4096ull * 2048 * 2);
  u16* qtmp   = (u16*)alloc(4096ull * 1536 * 2);
  u16* qh     = (u16*)alloc(65536ull * 96 * 2);    // (B,H,T,96)
  u16* kvall  = (u16*)alloc(4096ull * 288 * 2);
  u16* kvn    = (u16*)alloc(4096ull * 256 * 2);
  u16* kpe    = (u16*)alloc(4096ull * 32 * 2);
  float* P2   = (float*)alloc(4096ull * 64 * 4);
  float* C2   = (float*)alloc(2048ull * 64 * 4);
  u16* kvt    = (u16*)alloc(4096ull * 256 * 2);
  u16* kvb    = (u16*)alloc(4096ull * 2048 * 2);   // per-head [k_abs(64)|v(64)]
  u16* Kc     = (u16*)alloc(32ull * 1024 * 96 * 2);// (B,H,1024,96)
  u16* Vt     = (u16*)alloc(2048ull * 1024 * 2);   // (B,H,64,1024)
  u16* x      = (u16*)alloc(4096ull * 1024 * 2);

  dim3 tb(32, 8);
  transpose_f32_bf16<<<dim3(48, 64), tb, 0, stream>>>(wq,   wqT,   2048, 1536);
  transpose_f32_bf16<<<dim3(9,  64), tb, 0, stream>>>(wkva, wkvaT, 2048, 288);
  transpose_f32_bf16<<<dim3(64, 32), tb, 0, stream>>>(wo,   woT,   1024, 2048);
  cvt_f32_bf16<<<512,  256, 0, stream>>>(wkvb,  wkvbB,  2048 * 256);
  cvt_f32_bf16<<<8192, 256, 0, stream>>>(query, queryB, 4096 * 2048);
  cvt_f32_bf16<<<8192, 256, 0, stream>>>(key_,  keyB,   4096 * 2048);

  gemm128<0><<<dim3(12, 32), 256, 0, stream>>>(queryB, wqT, qtmp, 4096, 1536, 2048);
  gemm_bt<0,0><<<dim3(5, 64), 256, 0, stream>>>(keyB, wkvaT, kvall, 4096, 288, 2048);

  qsplit<<<12288, 256, 0, stream>>>(qtmp, pos, qh);
  ln_p2_rope<<<4096, 256, 0, stream>>>(kvall, gamma, beta, fcpw, fcpb, pos, kvn, P2, kpe);
  c2_kernel<<<2048, 64, 0, stream>>>(fccw, fccb, C2);
  kvt_kernel<<<4096, 64, 0, stream>>>(C2, P2, kvn, kvt);

  gemm128<0><<<dim3(16, 32), 256, 0, stream>>>(kvt, wkvbB, kvb, 4096, 2048, 256);
  vt_kernel<<<512, 256, 0, stream>>>(kvb, Vt);
  kc_gather<<<1536, 256, 0, stream>>>(kvb, kpe, Kc);
  attn_kernel<<<512, 256, 0, stream>>>(qh, kvb, kpe, Kc, Vt, x);

  gemm128<1><<<dim3(16, 32), 256, 0, stream>>>(x, woT, d_out, 4096, 2048, 1024);
}

// Round 5
// 392.846 us; speedup vs baseline: 1.3985x; 1.1282x over previous
//
#include <hip/hip_runtime.h>
#include <stddef.h>

typedef unsigned short u16;
typedef unsigned short u16x8 __attribute__((ext_vector_type(8)));
typedef short s16x8 __attribute__((ext_vector_type(8)));
typedef float f32x4 __attribute__((ext_vector_type(4)));

#define B_ 2
#define T_ 2048
#define E_ 2048
#define H_ 16

__device__ inline float us2f(u16 u){
  unsigned int i = ((unsigned int)u) << 16;
  return __builtin_bit_cast(float, i);
}
__device__ inline u16 f2us(float f){
  unsigned int x = __builtin_bit_cast(unsigned int, f);
  unsigned int r = (x + 0x7fffu + ((x >> 16) & 1u)) >> 16;
  return (u16)r;
}
__device__ inline f32x4 mfma32(s16x8 a, s16x8 b, f32x4 c){
  return __builtin_amdgcn_mfma_f32_16x16x32_bf16(a, b, c, 0, 0, 0);
}
__device__ inline s16x8 ld8(const u16* p){
  return __builtin_bit_cast(s16x8, *(const u16x8*)p);
}
// async global->LDS, 16B per lane; LDS dest = wave-uniform base + lane*16 (m97/m104)
__device__ inline void gload_lds16(const u16* g, u16* l){
  __builtin_amdgcn_global_load_lds(
      (const __attribute__((address_space(1))) unsigned int*)(g),
      (__attribute__((address_space(3))) unsigned int*)(l), 16, 0, 0);
}

// ---------------- f32 -> bf16 transpose (for weights) ----------------
__global__ void transpose_f32_bf16(const float* __restrict__ in, u16* __restrict__ out, int R, int C)
{
  __shared__ float tile[32][33];
  int c0 = blockIdx.x * 32, r0 = blockIdx.y * 32;
  int tx = threadIdx.x, ty = threadIdx.y;  // 32 x 8
  for (int i = ty; i < 32; i += 8){
    int r = r0 + i, c = c0 + tx;
    tile[i][tx] = (r < R && c < C) ? in[(size_t)r * C + c] : 0.f;
  }
  __syncthreads();
  for (int i = ty; i < 32; i += 8){
    int c = c0 + i, r = r0 + tx;
    if (c < C && r < R) out[(size_t)c * R + r] = f2us(tile[tx][i]);
  }
}

// ---------------- f32 -> bf16 flat convert ----------------
__global__ __launch_bounds__(256) void cvt_f32_bf16(const float* __restrict__ in,
    u16* __restrict__ out, int n)
{
  int i = (blockIdx.x * 256 + threadIdx.x) * 4;
  if (i + 3 < n){
    f32x4 v = *(const f32x4*)(in + i);
    out[i]   = f2us(v[0]); out[i+1] = f2us(v[1]);
    out[i+2] = f2us(v[2]); out[i+3] = f2us(v[3]);
  }
}

// ------- legacy 64x64 MFMA GEMM (for N=288 kvall only): C = A * Bt^T -------
template<int A_F32, int OUT_F32>
__global__ __launch_bounds__(256) void gemm_bt(const void* __restrict__ Ap,
    const u16* __restrict__ Bt, void* __restrict__ Cp, int M, int N, int K)
{
  __shared__ __align__(16) u16 As[64][40];
  __shared__ __align__(16) u16 Bs[64][40];
  const int tid  = threadIdx.x;
  const int lane = tid & 63;
  const int wid  = tid >> 6;
  const int quad = lane >> 4;
  const int col  = lane & 15;
  const int bm = blockIdx.y * 64;
  const int bn = blockIdx.x * 64;
  const int lr = tid >> 2;
  const int lc = (tid & 3) * 8;
  const int waveM = wid >> 1, waveN = wid & 1;

  f32x4 acc[2][2];
  for (int i = 0; i < 2; ++i)
    for (int j = 0; j < 2; ++j)
      acc[i][j] = (f32x4){0.f, 0.f, 0.f, 0.f};

  const u16x8 zero8 = {0,0,0,0,0,0,0,0};
  const bool bok = (bn + lr) < N;
  const u16*   arow16 = (const u16*)Ap   + (size_t)(bm + lr) * K + lc;
  const float* arow32 = (const float*)Ap + (size_t)(bm + lr) * K + lc;
  const u16* brow = Bt + (size_t)(bn + lr) * K + lc;

  for (int kk = 0; kk < K; kk += 32) {
    u16x8 av;
    if (A_F32) {
      f32x4 a0 = *(const f32x4*)(arow32 + kk);
      f32x4 a1 = *(const f32x4*)(arow32 + kk + 4);
      av[0]=f2us(a0[0]); av[1]=f2us(a0[1]); av[2]=f2us(a0[2]); av[3]=f2us(a0[3]);
      av[4]=f2us(a1[0]); av[5]=f2us(a1[1]); av[6]=f2us(a1[2]); av[7]=f2us(a1[3]);
    } else {
      av = *(const u16x8*)(arow16 + kk);
    }
    u16x8 bv = bok ? *(const u16x8*)(brow + kk) : zero8;
    __syncthreads();
    *(u16x8*)&As[lr][lc] = av;
    *(u16x8*)&Bs[lr][lc] = bv;
    __syncthreads();
    s16x8 af0 = ld8(&As[waveM*32 + col][quad*8]);
    s16x8 af1 = ld8(&As[waveM*32 + 16 + col][quad*8]);
    s16x8 bf0 = ld8(&Bs[waveN*32 + col][quad*8]);
    s16x8 bf1 = ld8(&Bs[waveN*32 + 16 + col][quad*8]);
    acc[0][0] = mfma32(af0, bf0, acc[0][0]);
    acc[0][1] = mfma32(af0, bf1, acc[0][1]);
    acc[1][0] = mfma32(af1, bf0, acc[1][0]);
    acc[1][1] = mfma32(af1, bf1, acc[1][1]);
  }
  for (int am = 0; am < 2; ++am)
    for (int bnn = 0; bnn < 2; ++bnn)
      for (int i = 0; i < 4; ++i) {
        int r = bm + waveM*32 + am*16 + quad*4 + i;
        int c = bn + waveN*32 + bnn*16 + col;
        if (c < N){
          if (OUT_F32) ((float*)Cp)[(size_t)r * N + c] = acc[am][bnn][i];
          else         ((u16*)Cp)[(size_t)r * N + c]   = f2us(acc[am][bnn][i]);
        }
      }
}

// ------- m97-style 128x128 GEMM: C(MxN) = A(MxK) * Bt(NxK)^T, bf16 in -------
template<int OUT_F32>
__global__ __launch_bounds__(256) void gemm128(const u16* __restrict__ A,
    const u16* __restrict__ Bt, void* __restrict__ Cp, int M, int N, int K)
{
  __shared__ __align__(16) u16 As[128 * 32];
  __shared__ __align__(16) u16 Bs[128 * 32];
  const int tid  = threadIdx.x;
  const int lane = tid & 63;
  const int wid  = tid >> 6;
  const int quad = lane >> 4;
  const int col  = lane & 15;
  const int bm = blockIdx.y * 128;
  const int bn = blockIdx.x * 128;
  const int waveM = wid >> 1, waveN = wid & 1;

  const int srow = wid * 16 + (lane >> 2);
  const int scol = (lane & 3) * 8;
  const u16* ga = A  + (size_t)(bm + srow) * K + scol;
  const u16* gb = Bt + (size_t)(bn + srow) * K + scol;
  const size_t rowskip = (size_t)64 * K;
  u16* lAs0 = &As[wid * 512];
  u16* lAs1 = &As[wid * 512 + 2048];
  u16* lBs0 = &Bs[wid * 512];
  u16* lBs1 = &Bs[wid * 512 + 2048];

  f32x4 acc[4][4] = {};

  for (int kk = 0; kk < K; kk += 32) {
    __syncthreads();
    gload_lds16(ga + kk,           lAs0);
    gload_lds16(ga + rowskip + kk, lAs1);
    gload_lds16(gb + kk,           lBs0);
    gload_lds16(gb + rowskip + kk, lBs1);
    __syncthreads();
    s16x8 af[4], bf[4];
#pragma unroll
    for (int i = 0; i < 4; ++i) af[i] = ld8(&As[(waveM*64 + i*16 + col) * 32 + quad*8]);
#pragma unroll
    for (int i = 0; i < 4; ++i) bf[i] = ld8(&Bs[(waveN*64 + i*16 + col) * 32 + quad*8]);
#pragma unroll
    for (int i = 0; i < 4; ++i)
#pragma unroll
      for (int j = 0; j < 4; ++j)
        acc[i][j] = mfma32(af[i], bf[j], acc[i][j]);
  }
#pragma unroll
  for (int i = 0; i < 4; ++i)
#pragma unroll
    for (int j = 0; j < 4; ++j)
#pragma unroll
      for (int r = 0; r < 4; ++r) {
        int row = bm + waveM*64 + i*16 + quad*4 + r;
        int c   = bn + waveN*64 + j*16 + col;
        if (OUT_F32) ((float*)Cp)[(size_t)row * N + c] = acc[i][j][r];
        else         ((u16*)Cp)[(size_t)row * N + c]   = f2us(acc[i][j][r]);
      }
}

// ------- split q -> qh (B,H,T,96), rope on dims 64..95; 8-elem chunks -------
__global__ __launch_bounds__(256) void qsplit(const u16* __restrict__ qtmp,
    const int* __restrict__ pos, u16* __restrict__ qh)
{
  int idx = blockIdx.x * 256 + threadIdx.x;      // chunk id
  if (idx >= B_*T_*H_*12) return;
  int c    = idx % 12;
  int rest = idx / 12;
  int h    = rest & 15;
  int row  = rest >> 4;            // b*T + t
  int t    = row & (T_ - 1);
  int b    = row >> 11;
  const u16* src = qtmp + (size_t)row * 1536 + h * 96;
  u16* dst = qh + ((size_t)(b * 16 + h) * T_ + t) * 96;
  u16x8 v = *(const u16x8*)(src + c * 8);
  if (c >= 8) {
    int i0 = (c - 8) * 4;
    float pp = (float)pos[t];
#pragma unroll
    for (int k = 0; k < 4; ++k){
      int i = i0 + k;
      float ang = pp * __expf((float)(2*i) * -0.28782313657f); // -ln(1e4)/32
      float cs = __cosf(ang), sn = __sinf(ang);
      float xr = us2f(v[2*k]), xi = us2f(v[2*k+1]);
      v[2*k]   = f2us(xr * cs - xi * sn);
      v[2*k+1] = f2us(xr * sn + xi * cs);
    }
  }
  *(u16x8*)(dst + c * 8) = v;
}

// --------- layernorm(kv) + P2 + rope(k_pe); exactly B_*T_ blocks ---------
__global__ __launch_bounds__(256) void ln_p2_rope(
    const u16* __restrict__ kvall, const float* __restrict__ gamma,
    const float* __restrict__ beta, const float* __restrict__ fcpw,
    const float* __restrict__ fcpb, const int* __restrict__ pos,
    u16* __restrict__ kvn, float* __restrict__ P2, u16* __restrict__ kpe)
{
  const int row = blockIdx.x;      // b*T + t
  if (row >= B_ * T_) return;
  const int tid = threadIdx.x;
  const int lane = tid & 63, wid = tid >> 6;
  __shared__ float kvs[256];
  __shared__ float part[256];
  __shared__ float redS[4], redS2[4];
  const u16* src = kvall + (size_t)row * 288;
  float v = us2f(src[tid]);
  float s1 = v, s2 = v * v;
  for (int off = 1; off < 64; off <<= 1){
    s1 += __shfl_xor(s1, off);
    s2 += __shfl_xor(s2, off);
  }
  if (lane == 0){ redS[wid] = s1; redS2[wid] = s2; }
  __syncthreads();
  float S  = redS[0] + redS[1] + redS[2] + redS[3];
  float Q  = redS2[0] + redS2[1] + redS2[2] + redS2[3];
  float mean = S * (1.f / 256.f);
  float var  = Q * (1.f / 256.f) - mean * mean;
  float rstd = rsqrtf(var + 1e-5f);
  float xn = (v - mean) * rstd * gamma[tid] + beta[tid];
  kvs[tid] = xn;
  kvn[(size_t)row * 256 + tid] = f2us(xn);
  __syncthreads();
  // P2 partials: thread (pp,oc) covers rows pp*64..pp*64+63 of the 256-dot
  {
    int oc = tid & 63, pp = tid >> 6;
    float acc = 0.f;
#pragma unroll 8
    for (int c = pp * 64; c < pp * 64 + 64; ++c)
      acc += kvs[c] * fcpw[c * 64 + oc];
    part[tid] = acc;
  }
  __syncthreads();
  if (tid < 64) {
    P2[(size_t)row * 64 + tid] = fcpb[tid] + part[tid] + part[64 + tid]
                               + part[128 + tid] + part[192 + tid];
  } else if (tid < 80) {
    int i = tid - 64;
    int t = row & (T_ - 1);
    float ang = (float)pos[t] * __expf((float)(2*i) * -0.28782313657f);
    float c = __cosf(ang), s = __sinf(ang);
    float xr = us2f(src[256 + 2*i]);
    float xi = us2f(src[257 + 2*i]);
    kpe[(size_t)row * 32 + 2*i]     = f2us(xr * c - xi * s);
    kpe[(size_t)row * 32 + 2*i + 1] = f2us(xr * s + xi * c);
  }
}

// ---------------- C2[t] = sinusoid_pe(t/2) @ fc_c_w + b -----------------------
__global__ __launch_bounds__(64) void c2_kernel(const float* __restrict__ fccw,
    const float* __restrict__ fccb, float* __restrict__ C2)
{
  const int t = blockIdx.x, tid = threadIdx.x;
  __shared__ float pe[256];
  float p = (float)(t >> 1);
  for (int i = tid; i < 128; i += 64){
    float div = expf((float)(2*i) * -0.03597789207f);  // -ln(1e4)/256
    float a = p * div;
    pe[2*i]   = sinf(a);
    pe[2*i+1] = cosf(a);
  }
  __syncthreads();
  float acc = fccb[tid];
  for (int c = 0; c < 256; ++c) acc += pe[c] * fccw[c * 64 + tid];
  C2[t * 64 + tid] = acc;
}

// ---------------- kv_t: block-diag (DR=2) temporal conv; B_*T_ blocks --------
__global__ __launch_bounds__(64) void kvt_kernel(const float* __restrict__ C2,
    const float* __restrict__ P2, const u16* __restrict__ kvn, u16* __restrict__ kvt)
{
  const int row = blockIdx.x;       // b*T + t
  if (row >= B_ * T_) return;
  const int lane = threadIdx.x;
  const int t = row & (T_ - 1);
  float c2v = C2[t * 64 + lane];
  float da = c2v * P2[(size_t)row * 64 + lane];
  for (int off = 1; off < 64; off <<= 1) da += __shfl_xor(da, off);
  float wtt = 1.f / (1.f + __expf(-da));
  const bool odd = (t & 1);
  float wts = 0.f;
  if (odd){
    float db = c2v * P2[(size_t)(row - 1) * 64 + lane];
    for (int off = 1; off < 64; off <<= 1) db += __shfl_xor(db, off);
    wts = 1.f / (1.f + __expf(-db));
  }
  for (int c = lane; c < 256; c += 64){
    float val = wtt * us2f(kvn[(size_t)row * 256 + c]);
    if (odd) val += wts * us2f(kvn[(size_t)(row - 1) * 256 + c]);
    kvt[(size_t)row * 256 + c] = f2us(val);
  }
}

// ------- Vt: gather odd-position v rows from kvb, transpose -> (B,H,64,1024) -------
__global__ __launch_bounds__(256) void vt_kernel(const u16* __restrict__ kvb, u16* __restrict__ Vt)
{
  const int bid = blockIdx.x;
  const int jt = bid & 15;
  const int h  = (bid >> 4) & 15;
  const int b  = bid >> 8;
  const int tid = threadIdx.x;
  __shared__ __align__(16) u16 tile[64][72];
  const int jl = tid >> 2;
  const int dseg = (tid & 3) * 16;
  const int j0 = jt * 64;
  {
    int s_ = 2 * (j0 + jl) + 1;
    const u16* src = kvb + ((size_t)(b * T_ + s_)) * 2048 + h * 128 + 64 + dseg;
    *(u16x8*)&tile[jl][dseg]     = *(const u16x8*)(src);
    *(u16x8*)&tile[jl][dseg + 8] = *(const u16x8*)(src + 8);
  }
  __syncthreads();
  const int dl = tid >> 2;
  const int jseg = (tid & 3) * 16;
  u16* dst = Vt + ((size_t)(b * 16 + h) * 64 + dl) * 1024 + j0 + jseg;
  u16x8 o;
  for (int r = 0; r < 8; ++r) o[r] = tile[jseg + r][dl];
  *(u16x8*)dst = o;
  for (int r = 0; r < 8; ++r) o[r] = tile[jseg + 8 + r][dl];
  *(u16x8*)(dst + 8) = o;
}

// ------- Kc: gather compressed keys -> (B,H,1024,96) = [k_abs(64)|kpe(32)] -------
__global__ __launch_bounds__(256) void kc_gather(const u16* __restrict__ kvb,
    const u16* __restrict__ kpe, u16* __restrict__ Kc)
{
  int idx = blockIdx.x * 256 + threadIdx.x;    // chunk of 8 elems
  int c  = idx % 12;
  int j  = (idx / 12) & 1023;
  int bh = idx / (12 * 1024);
  if (bh >= B_ * H_) return;
  int b = bh >> 4, h = bh & 15;
  int t = 2 * j + 1;
  u16x8 v;
  if (c < 8) v = *(const u16x8*)(kvb + ((size_t)(b * T_ + t)) * 2048 + h * 128 + c * 8);
  else       v = *(const u16x8*)(kpe + ((size_t)(b * T_ + t)) * 32 + (c - 8) * 8);
  *(u16x8*)(Kc + ((size_t)bh * 1024 + j) * 96 + c * 8) = v;
}

// ---- flash attention: fixed-max softmax, 128-key LDS chunks, paired q-tiles ----
__global__ __launch_bounds__(256) void attn_kernel(
    const u16* __restrict__ qh, const u16* __restrict__ kvb,
    const u16* __restrict__ kpe, const u16* __restrict__ Kc,
    const u16* __restrict__ Vt, u16* __restrict__ xout)
{
  __shared__ __align__(16) u16 Ks[128 * 96];       // 128 keys x 96 dims, flat
  __shared__ __align__(16) u16 Vs[64][136];        // 64 dims x 128 keys, padded
  __shared__ __align__(16) u16 pbufA[4][16 * 136]; // per-wave P: 16 q x 128 keys
  const int tid  = threadIdx.x;
  const int wid  = tid >> 6;
  const int lane = tid & 63;
  const int quad = lane >> 4;
  const int col  = lane & 15;
  const int pair = blockIdx.x & 15;
  const int h    = (blockIdx.x >> 4) & 15;
  const int b    = blockIdx.x >> 8;
  const int bh   = b * H_ + h;
  u16* pbuf = pbufA[wid];
  const float scale = 0.10206207262f;   // 96^-0.5
  const u16* KcH = Kc + (size_t)bh * 1024 * 96;
  const u16* VtH = Vt + (size_t)bh * 64 * 1024;

  for (int ph = 0; ph < 2; ++ph) {
    const int qt = ph ? (31 - pair) : pair;
    const int t0 = qt * 64 + wid * 16;

    s16x8 aq0, aq1, aq2;
    {
      const u16* qrow = qh + ((size_t)bh * T_ + t0 + col) * 96;
      aq0 = ld8(qrow + quad * 8);
      aq1 = ld8(qrow + 32 + quad * 8);
      aq2 = ld8(qrow + 64 + quad * 8);
    }
    // self score (lane col holds row col's score)
    float sself;
    {
      const int t = t0 + col;
      const u16* qrow = qh + ((size_t)bh * T_ + t) * 96;
      const u16* ka = kvb + ((size_t)(b * T_ + t)) * 2048 + h * 128;
      const u16* kp = kpe + ((size_t)(b * T_ + t)) * 32;
      float a = 0.f;
      for (int d = 0; d < 64; ++d) a += us2f(qrow[d]) * us2f(ka[d]);
      for (int d = 0; d < 32; ++d) a += us2f(qrow[64 + d]) * us2f(kp[d]);
      sself = a * scale;
    }
    float es[4], lacc[4];
    f32x4 O[4];
#pragma unroll
    for (int i = 0; i < 4; ++i){
      es[i] = __expf(__shfl(sself, quad * 4 + i));
      lacc[i] = 0.f;
    }
#pragma unroll
    for (int nt = 0; nt < 4; ++nt)
#pragma unroll
      for (int i = 0; i < 4; ++i){
        int t = t0 + quad * 4 + i;
        O[nt][i] = es[i] * us2f(kvb[((size_t)(b * T_ + t)) * 2048 + h * 128 + 64 + nt * 16 + col]);
      }

    const int nb = (qt * 32 + 31 + 127) >> 7;   // 128-key blocks, block-uniform
    for (int blk = 0; blk < nb; ++blk) {
      const int jb = blk * 128;
      __syncthreads();
      {
        // Ks: flat 128x96 via global_load_lds (24 x 1KB, coalesced)
        const u16* gk = KcH + (size_t)jb * 96 + (size_t)(wid * 6) * 512 + lane * 8;
        u16* lk = &Ks[(wid * 6) * 512];
#pragma unroll
        for (int k = 0; k < 6; ++k)
          gload_lds16(gk + k * 512, lk + k * 512);
        // Vs: 64 dims x 128 keys
        int d = tid >> 2, c4 = tid & 3;
        const u16* gv = VtH + (size_t)d * 1024 + jb + c4 * 32;
        u16* lv = &Vs[d][c4 * 32];
#pragma unroll
        for (int k = 0; k < 4; ++k)
          *(u16x8*)(lv + k * 8) = *(const u16x8*)(gv + k * 8);
      }
      __syncthreads();
#pragma unroll
      for (int cc = 0; cc < 4; ++cc){
        const u16* k0 = &Ks[(cc * 32 + col) * 96];
        const u16* k1 = &Ks[(cc * 32 + 16 + col) * 96];
        f32x4 s0 = {0,0,0,0}, s1 = {0,0,0,0};
        s0 = mfma32(aq0, ld8(k0 + quad * 8), s0);
        s0 = mfma32(aq1, ld8(k0 + 32 + quad * 8), s0);
        s0 = mfma32(aq2, ld8(k0 + 64 + quad * 8), s0);
        s1 = mfma32(aq0, ld8(k1 + quad * 8), s1);
        s1 = mfma32(aq1, ld8(k1 + 32 + quad * 8), s1);
        s1 = mfma32(aq2, ld8(k1 + 64 + quad * 8), s1);
        int key0 = jb + cc * 32 + col;
#pragma unroll
        for (int i = 0; i < 4; ++i){
          int lim = (t0 + quad * 4 + i) >> 1;
          float p0 = (key0 < lim)      ? __expf(s0[i] * scale) : 0.f;
          float p1 = (key0 + 16 < lim) ? __expf(s1[i] * scale) : 0.f;
          lacc[i] += p0 + p1;
          pbuf[(quad * 4 + i) * 136 + cc * 32 + col]      = f2us(p0);
          pbuf[(quad * 4 + i) * 136 + cc * 32 + 16 + col] = f2us(p1);
        }
      }
      asm volatile("s_waitcnt lgkmcnt(0)" ::: "memory");
#pragma unroll
      for (int cc = 0; cc < 4; ++cc){
        s16x8 pf = ld8(&pbuf[col * 136 + cc * 32 + quad * 8]);
#pragma unroll
        for (int nt = 0; nt < 4; ++nt)
          O[nt] = mfma32(pf, ld8(&Vs[nt * 16 + col][cc * 32 + quad * 8]), O[nt]);
      }
    }
    // final l reduction (once per phase, not per iter)
#pragma unroll
    for (int i = 0; i < 4; ++i){
      float l = lacc[i];
      l += __shfl_xor(l, 1);
      l += __shfl_xor(l, 2);
      l += __shfl_xor(l, 4);
      l += __shfl_xor(l, 8);
      lacc[i] = es[i] + l;
    }
#pragma unroll
    for (int nt = 0; nt < 4; ++nt)
#pragma unroll
      for (int i = 0; i < 4; ++i){
        int t = t0 + quad * 4 + i;
        xout[((size_t)(b * T_ + t)) * 1024 + h * 64 + nt * 16 + col] = f2us(O[nt][i] / lacc[i]);
      }
    __syncthreads();   // protect Ks/Vs before next phase restages
  }
}

extern "C" void kernel_launch(void* const* d_in, const int* in_sizes, int n_in,
                              void* d_out, int out_size, void* d_ws, size_t ws_size,
                              hipStream_t stream)
{
  (void)in_sizes; (void)n_in; (void)out_size; (void)ws_size;
  const float* query = (const float*)d_in[0];
  const float* key_  = (const float*)d_in[1];
  const int*   pos   = (const int*)d_in[3];
  const float* wq    = (const float*)d_in[4];
  const float* wkva  = (const float*)d_in[5];
  const float* gamma = (const float*)d_in[6];
  const float* beta  = (const float*)d_in[7];
  const float* wkvb  = (const float*)d_in[8];
  const float* wo    = (const float*)d_in[9];
  const float* fccw  = (const float*)d_in[10];
  const float* fccb  = (const float*)d_in[11];
  const float* fcpw  = (const float*)d_in[12];
  const float* fcpb  = (const float*)d_in[13];

  char* p = (char*)d_ws;
  auto alloc = [&](size_t bytes) -> void* {
    void* r = (void*)p;
    p += (bytes + 255) & ~(size_t)255;
    return r;
  };
  u16* wqT    = (u16*)alloc(1536ull * 2048 * 2);
  u16* wkvaT  = (u16*)alloc(288ull  * 2048 * 2);
  u16* woT    = (u16*)alloc(2048ull * 1024 * 2);
  u16* wkvbB  = (u16*)alloc(2048ull * 256 * 2);
  u16* queryB = (u16*)alloc(4096ull * 2048 * 2);
  u16* keyB   = (u16*)alloc(4096ull * 2048 * 2);
  u16* qtmp   = (u16*)alloc(4096ull * 1536 * 2);
  u16* qh     = (u16*)alloc(65536ull * 96 * 2);    // (B,H,T,96)
  u16* kvall  = (u16*)alloc(4096ull * 288 * 2);
  u16* kvn    = (u16*)alloc(4096ull * 256 * 2);
  u16* kpe    = (u16*)alloc(4096ull * 32 * 2);
  float* P2   = (float*)alloc(4096ull * 64 * 4);
  float* C2   = (float*)alloc(2048ull * 64 * 4);
  u16* kvt    = (u16*)alloc(4096ull * 256 * 2);
  u16* kvb    = (u16*)alloc(4096ull * 2048 * 2);   // per-head [k_abs(64)|v(64)]
  u16* Kc     = (u16*)alloc(32ull * 1024 * 96 * 2);// (B,H,1024,96)
  u16* Vt     = (u16*)alloc(2048ull * 1024 * 2);   // (B,H,64,1024)
  u16* x      = (u16*)alloc(4096ull * 1024 * 2);

  dim3 tb(32, 8);
  transpose_f32_bf16<<<dim3(48, 64), tb, 0, stream>>>(wq,   wqT,   2048, 1536);
  transpose_f32_bf16<<<dim3(9,  64), tb, 0, stream>>>(wkva, wkvaT, 2048, 288);
  transpose_f32_bf16<<<dim3(64, 32), tb, 0, stream>>>(wo,   woT,   1024, 2048);
  cvt_f32_bf16<<<512,  256, 0, stream>>>(wkvb,  wkvbB,  2048 * 256);
  cvt_f32_bf16<<<8192, 256, 0, stream>>>(query, queryB, 4096 * 2048);
  cvt_f32_bf16<<<8192, 256, 0, stream>>>(key_,  keyB,   4096 * 2048);

  gemm128<0><<<dim3(12, 32), 256, 0, stream>>>(queryB, wqT, qtmp, 4096, 1536, 2048);
  gemm_bt<0,0><<<dim3(5, 64), 256, 0, stream>>>(keyB, wkvaT, kvall, 4096, 288, 2048);

  qsplit<<<3072, 256, 0, stream>>>(qtmp, pos, qh);
  ln_p2_rope<<<4096, 256, 0, stream>>>(kvall, gamma, beta, fcpw, fcpb, pos, kvn, P2, kpe);
  c2_kernel<<<2048, 64, 0, stream>>>(fccw, fccb, C2);
  kvt_kernel<<<4096, 64, 0, stream>>>(C2, P2, kvn, kvt);

  gemm128<0><<<dim3(16, 32), 256, 0, stream>>>(kvt, wkvbB, kvb, 4096, 2048, 256);
  vt_kernel<<<512, 256, 0, stream>>>(kvb, Vt);
  kc_gather<<<1536, 256, 0, stream>>>(kvb, kpe, Kc);
  attn_kernel<<<512, 256, 0, stream>>>(qh, kvb, kpe, Kc, Vt, x);

  gemm128<1><<<dim3(16, 32), 256, 0, stream>>>(x, woT, d_out, 4096, 2048, 1024);
}

// Round 6
// 362.692 us; speedup vs baseline: 1.5148x; 1.0831x over previous
//
#include <hip/hip_runtime.h>
#include <stddef.h>

typedef unsigned short u16;
typedef unsigned short u16x8 __attribute__((ext_vector_type(8)));
typedef short s16x8 __attribute__((ext_vector_type(8)));
typedef float f32x4 __attribute__((ext_vector_type(4)));

#define B_ 2
#define T_ 2048
#define E_ 2048
#define H_ 16

__device__ inline float us2f(u16 u){
  unsigned int i = ((unsigned int)u) << 16;
  return __builtin_bit_cast(float, i);
}
__device__ inline u16 f2us(float f){
  unsigned int x = __builtin_bit_cast(unsigned int, f);
  unsigned int r = (x + 0x7fffu + ((x >> 16) & 1u)) >> 16;
  return (u16)r;
}
__device__ inline f32x4 mfma32(s16x8 a, s16x8 b, f32x4 c){
  return __builtin_amdgcn_mfma_f32_16x16x32_bf16(a, b, c, 0, 0, 0);
}
__device__ inline s16x8 ld8(const u16* p){
  return __builtin_bit_cast(s16x8, *(const u16x8*)p);
}
// async global->LDS, 16B per lane; LDS dest = wave-uniform base + lane*16 (m97/m104)
__device__ inline void gload_lds16(const u16* g, u16* l){
  __builtin_amdgcn_global_load_lds(
      (const __attribute__((address_space(1))) unsigned int*)(g),
      (__attribute__((address_space(3))) unsigned int*)(l), 16, 0, 0);
}

// ---- fused weight prep: 3 transposes (f32->bf16) + wkvb flat cvt, one launch ----
__global__ __launch_bounds__(256) void prep_weights(
    const float* __restrict__ wq, const float* __restrict__ wkva,
    const float* __restrict__ wo, const float* __restrict__ wkvb,
    u16* __restrict__ wqT, u16* __restrict__ wkvaT, u16* __restrict__ woT,
    u16* __restrict__ wkvbB)
{
  __shared__ float tile[32][33];
  const int bid = blockIdx.x;
  const int tid = threadIdx.x;
  if (bid < 5696) {
    const float* in; u16* out; int R, C, bx, by;
    if (bid < 3072)      { in = wq;   out = wqT;   R = 2048; C = 1536; bx = bid % 48;          by = bid / 48; }
    else if (bid < 3648) { in = wkva; out = wkvaT; R = 2048; C = 288;  bx = (bid-3072) % 9;    by = (bid-3072) / 9; }
    else                 { in = wo;   out = woT;   R = 1024; C = 2048; bx = (bid-3648) % 64;   by = (bid-3648) / 64; }
    int tx = tid & 31, ty = tid >> 5;   // 32 x 8
    int c0 = bx * 32, r0 = by * 32;
    for (int i = ty; i < 32; i += 8){
      int r = r0 + i, c = c0 + tx;
      tile[i][tx] = (r < R && c < C) ? in[(size_t)r * C + c] : 0.f;
    }
    __syncthreads();
    for (int i = ty; i < 32; i += 8){
      int c = c0 + i, r = r0 + tx;
      if (c < C && r < R) out[(size_t)c * R + r] = f2us(tile[tx][i]);
    }
  } else {
    int i = (bid - 5696) * 1024 + tid * 4;   // 512 blocks x 1024 elems = 2048*256
    f32x4 v = *(const f32x4*)(wkvb + i);
    wkvbB[i]   = f2us(v[0]); wkvbB[i+1] = f2us(v[1]);
    wkvbB[i+2] = f2us(v[2]); wkvbB[i+3] = f2us(v[3]);
  }
}

// ---------------- f32 -> bf16 convert, two tensors in one launch ----------------
__global__ __launch_bounds__(256) void cvt2_f32_bf16(const float* __restrict__ a,
    const float* __restrict__ b, u16* __restrict__ oa, u16* __restrict__ ob, int n_each)
{
  int idx = (blockIdx.x * 256 + threadIdx.x) * 4;
  const float* in; u16* out; int i;
  if (idx < n_each){ in = a; out = oa; i = idx; }
  else             { in = b; out = ob; i = idx - n_each; }
  if (i + 3 < n_each){
    f32x4 v = *(const f32x4*)(in + i);
    out[i]   = f2us(v[0]); out[i+1] = f2us(v[1]);
    out[i+2] = f2us(v[2]); out[i+3] = f2us(v[3]);
  }
}

// ------- legacy 64x64 MFMA GEMM (for N=288 kvall only): C = A * Bt^T -------
template<int A_F32, int OUT_F32>
__global__ __launch_bounds__(256) void gemm_bt(const void* __restrict__ Ap,
    const u16* __restrict__ Bt, void* __restrict__ Cp, int M, int N, int K)
{
  __shared__ __align__(16) u16 As[64][40];
  __shared__ __align__(16) u16 Bs[64][40];
  const int tid  = threadIdx.x;
  const int lane = tid & 63;
  const int wid  = tid >> 6;
  const int quad = lane >> 4;
  const int col  = lane & 15;
  const int bm = blockIdx.y * 64;
  const int bn = blockIdx.x * 64;
  const int lr = tid >> 2;
  const int lc = (tid & 3) * 8;
  const int waveM = wid >> 1, waveN = wid & 1;

  f32x4 acc[2][2];
  for (int i = 0; i < 2; ++i)
    for (int j = 0; j < 2; ++j)
      acc[i][j] = (f32x4){0.f, 0.f, 0.f, 0.f};

  const u16x8 zero8 = {0,0,0,0,0,0,0,0};
  const bool bok = (bn + lr) < N;
  const u16*   arow16 = (const u16*)Ap   + (size_t)(bm + lr) * K + lc;
  const float* arow32 = (const float*)Ap + (size_t)(bm + lr) * K + lc;
  const u16* brow = Bt + (size_t)(bn + lr) * K + lc;

  for (int kk = 0; kk < K; kk += 32) {
    u16x8 av;
    if (A_F32) {
      f32x4 a0 = *(const f32x4*)(arow32 + kk);
      f32x4 a1 = *(const f32x4*)(arow32 + kk + 4);
      av[0]=f2us(a0[0]); av[1]=f2us(a0[1]); av[2]=f2us(a0[2]); av[3]=f2us(a0[3]);
      av[4]=f2us(a1[0]); av[5]=f2us(a1[1]); av[6]=f2us(a1[2]); av[7]=f2us(a1[3]);
    } else {
      av = *(const u16x8*)(arow16 + kk);
    }
    u16x8 bv = bok ? *(const u16x8*)(brow + kk) : zero8;
    __syncthreads();
    *(u16x8*)&As[lr][lc] = av;
    *(u16x8*)&Bs[lr][lc] = bv;
    __syncthreads();
    s16x8 af0 = ld8(&As[waveM*32 + col][quad*8]);
    s16x8 af1 = ld8(&As[waveM*32 + 16 + col][quad*8]);
    s16x8 bf0 = ld8(&Bs[waveN*32 + col][quad*8]);
    s16x8 bf1 = ld8(&Bs[waveN*32 + 16 + col][quad*8]);
    acc[0][0] = mfma32(af0, bf0, acc[0][0]);
    acc[0][1] = mfma32(af0, bf1, acc[0][1]);
    acc[1][0] = mfma32(af1, bf0, acc[1][0]);
    acc[1][1] = mfma32(af1, bf1, acc[1][1]);
  }
  for (int am = 0; am < 2; ++am)
    for (int bnn = 0; bnn < 2; ++bnn)
      for (int i = 0; i < 4; ++i) {
        int r = bm + waveM*32 + am*16 + quad*4 + i;
        int c = bn + waveN*32 + bnn*16 + col;
        if (c < N){
          if (OUT_F32) ((float*)Cp)[(size_t)r * N + c] = acc[am][bnn][i];
          else         ((u16*)Cp)[(size_t)r * N + c]   = f2us(acc[am][bnn][i]);
        }
      }
}

// ------- m97-style 128x128 GEMM: C(MxN) = A(MxK) * Bt(NxK)^T, bf16 in -------
template<int OUT_F32>
__global__ __launch_bounds__(256) void gemm128(const u16* __restrict__ A,
    const u16* __restrict__ Bt, void* __restrict__ Cp, int M, int N, int K)
{
  __shared__ __align__(16) u16 As[128 * 32];
  __shared__ __align__(16) u16 Bs[128 * 32];
  const int tid  = threadIdx.x;
  const int lane = tid & 63;
  const int wid  = tid >> 6;
  const int quad = lane >> 4;
  const int col  = lane & 15;
  const int bm = blockIdx.y * 128;
  const int bn = blockIdx.x * 128;
  const int waveM = wid >> 1, waveN = wid & 1;

  const int srow = wid * 16 + (lane >> 2);
  const int scol = (lane & 3) * 8;
  const u16* ga = A  + (size_t)(bm + srow) * K + scol;
  const u16* gb = Bt + (size_t)(bn + srow) * K + scol;
  const size_t rowskip = (size_t)64 * K;
  u16* lAs0 = &As[wid * 512];
  u16* lAs1 = &As[wid * 512 + 2048];
  u16* lBs0 = &Bs[wid * 512];
  u16* lBs1 = &Bs[wid * 512 + 2048];

  f32x4 acc[4][4] = {};

  for (int kk = 0; kk < K; kk += 32) {
    __syncthreads();
    gload_lds16(ga + kk,           lAs0);
    gload_lds16(ga + rowskip + kk, lAs1);
    gload_lds16(gb + kk,           lBs0);
    gload_lds16(gb + rowskip + kk, lBs1);
    __syncthreads();
    s16x8 af[4], bf[4];
#pragma unroll
    for (int i = 0; i < 4; ++i) af[i] = ld8(&As[(waveM*64 + i*16 + col) * 32 + quad*8]);
#pragma unroll
    for (int i = 0; i < 4; ++i) bf[i] = ld8(&Bs[(waveN*64 + i*16 + col) * 32 + quad*8]);
#pragma unroll
    for (int i = 0; i < 4; ++i)
#pragma unroll
      for (int j = 0; j < 4; ++j)
        acc[i][j] = mfma32(af[i], bf[j], acc[i][j]);
  }
#pragma unroll
  for (int i = 0; i < 4; ++i)
#pragma unroll
    for (int j = 0; j < 4; ++j)
#pragma unroll
      for (int r = 0; r < 4; ++r) {
        int row = bm + waveM*64 + i*16 + quad*4 + r;
        int c   = bn + waveN*64 + j*16 + col;
        if (OUT_F32) ((float*)Cp)[(size_t)row * N + c] = acc[i][j][r];
        else         ((u16*)Cp)[(size_t)row * N + c]   = f2us(acc[i][j][r]);
      }
}

// ------- split-K=2 128x128 GEMM: half kh computes A[:,kh*Klen:+Klen] @ Bt^T -> Cp_kh (bf16) -------
// K = full row stride; Klen = K/2; grid (N/128, M/128, 2). 2x blocks vs gemm128 -> fixes grid starvation.
__global__ __launch_bounds__(256) void gemm128_sk(const u16* __restrict__ A,
    const u16* __restrict__ Bt, u16* __restrict__ Cp0, u16* __restrict__ Cp1,
    int M, int N, int K, int Klen)
{
  __shared__ __align__(16) u16 As[128 * 32];
  __shared__ __align__(16) u16 Bs[128 * 32];
  const int tid  = threadIdx.x;
  const int lane = tid & 63;
  const int wid  = tid >> 6;
  const int quad = lane >> 4;
  const int col  = lane & 15;
  const int bm = blockIdx.y * 128;
  const int bn = blockIdx.x * 128;
  const int kh = blockIdx.z;
  const int waveM = wid >> 1, waveN = wid & 1;

  const int srow = wid * 16 + (lane >> 2);
  const int scol = (lane & 3) * 8;
  const u16* ga = A  + (size_t)(bm + srow) * K + kh * Klen + scol;
  const u16* gb = Bt + (size_t)(bn + srow) * K + kh * Klen + scol;
  const size_t rowskip = (size_t)64 * K;
  u16* lAs0 = &As[wid * 512];
  u16* lAs1 = &As[wid * 512 + 2048];
  u16* lBs0 = &Bs[wid * 512];
  u16* lBs1 = &Bs[wid * 512 + 2048];
  u16* Cp = kh ? Cp1 : Cp0;

  f32x4 acc[4][4] = {};

  for (int kk = 0; kk < Klen; kk += 32) {
    __syncthreads();
    gload_lds16(ga + kk,           lAs0);
    gload_lds16(ga + rowskip + kk, lAs1);
    gload_lds16(gb + kk,           lBs0);
    gload_lds16(gb + rowskip + kk, lBs1);
    __syncthreads();
    s16x8 af[4], bf[4];
#pragma unroll
    for (int i = 0; i < 4; ++i) af[i] = ld8(&As[(waveM*64 + i*16 + col) * 32 + quad*8]);
#pragma unroll
    for (int i = 0; i < 4; ++i) bf[i] = ld8(&Bs[(waveN*64 + i*16 + col) * 32 + quad*8]);
#pragma unroll
    for (int i = 0; i < 4; ++i)
#pragma unroll
      for (int j = 0; j < 4; ++j)
        acc[i][j] = mfma32(af[i], bf[j], acc[i][j]);
  }
#pragma unroll
  for (int i = 0; i < 4; ++i)
#pragma unroll
    for (int j = 0; j < 4; ++j)
#pragma unroll
      for (int r = 0; r < 4; ++r) {
        int row = bm + waveM*64 + i*16 + quad*4 + r;
        int c   = bn + waveN*64 + j*16 + col;
        Cp[(size_t)row * N + c] = f2us(acc[i][j][r]);
      }
}

// ------- qsplit: combine split-K partials, rope dims 64..95, -> qh (B,H,T,96) -------
__global__ __launch_bounds__(256) void qsplit(const u16* __restrict__ qp0,
    const u16* __restrict__ qp1, const int* __restrict__ pos, u16* __restrict__ qh)
{
  int idx = blockIdx.x * 256 + threadIdx.x;      // 8-elem chunk id
  if (idx >= B_*T_*H_*12) return;
  int c    = idx % 12;
  int rest = idx / 12;
  int h    = rest & 15;
  int row  = rest >> 4;            // b*T + t
  int t    = row & (T_ - 1);
  int b    = row >> 11;
  size_t off = (size_t)row * 1536 + h * 96 + c * 8;
  u16x8 v0 = *(const u16x8*)(qp0 + off);
  u16x8 v1 = *(const u16x8*)(qp1 + off);
  u16x8 v;
  if (c < 8) {
#pragma unroll
    for (int k = 0; k < 8; ++k) v[k] = f2us(us2f(v0[k]) + us2f(v1[k]));
  } else {
    int i0 = (c - 8) * 4;
    float pp = (float)pos[t];
#pragma unroll
    for (int k = 0; k < 4; ++k){
      int i = i0 + k;
      float ang = pp * __expf((float)(2*i) * -0.28782313657f); // -ln(1e4)/32
      float cs = __cosf(ang), sn = __sinf(ang);
      float xr = us2f(v0[2*k])   + us2f(v1[2*k]);
      float xi = us2f(v0[2*k+1]) + us2f(v1[2*k+1]);
      v[2*k]   = f2us(xr * cs - xi * sn);
      v[2*k+1] = f2us(xr * sn + xi * cs);
    }
  }
  u16* dst = qh + ((size_t)(b * 16 + h) * T_ + t) * 96;
  *(u16x8*)(dst + c * 8) = v;
}

// --------- layernorm(kv) + P2 + rope(k_pe); exactly B_*T_ blocks ---------
__global__ __launch_bounds__(256) void ln_p2_rope(
    const u16* __restrict__ kvall, const float* __restrict__ gamma,
    const float* __restrict__ beta, const float* __restrict__ fcpw,
    const float* __restrict__ fcpb, const int* __restrict__ pos,
    u16* __restrict__ kvn, float* __restrict__ P2, u16* __restrict__ kpe)
{
  const int row = blockIdx.x;      // b*T + t
  if (row >= B_ * T_) return;
  const int tid = threadIdx.x;
  const int lane = tid & 63, wid = tid >> 6;
  __shared__ float kvs[256];
  __shared__ float part[256];
  __shared__ float redS[4], redS2[4];
  const u16* src = kvall + (size_t)row * 288;
  float v = us2f(src[tid]);
  float s1 = v, s2 = v * v;
  for (int off = 1; off < 64; off <<= 1){
    s1 += __shfl_xor(s1, off);
    s2 += __shfl_xor(s2, off);
  }
  if (lane == 0){ redS[wid] = s1; redS2[wid] = s2; }
  __syncthreads();
  float S  = redS[0] + redS[1] + redS[2] + redS[3];
  float Q  = redS2[0] + redS2[1] + redS2[2] + redS2[3];
  float mean = S * (1.f / 256.f);
  float var  = Q * (1.f / 256.f) - mean * mean;
  float rstd = rsqrtf(var + 1e-5f);
  float xn = (v - mean) * rstd * gamma[tid] + beta[tid];
  kvs[tid] = xn;
  kvn[(size_t)row * 256 + tid] = f2us(xn);
  __syncthreads();
  {
    int oc = tid & 63, pp = tid >> 6;
    float acc = 0.f;
#pragma unroll 8
    for (int c = pp * 64; c < pp * 64 + 64; ++c)
      acc += kvs[c] * fcpw[c * 64 + oc];
    part[tid] = acc;
  }
  __syncthreads();
  if (tid < 64) {
    P2[(size_t)row * 64 + tid] = fcpb[tid] + part[tid] + part[64 + tid]
                               + part[128 + tid] + part[192 + tid];
  } else if (tid < 80) {
    int i = tid - 64;
    int t = row & (T_ - 1);
    float ang = (float)pos[t] * __expf((float)(2*i) * -0.28782313657f);
    float c = __cosf(ang), s = __sinf(ang);
    float xr = us2f(src[256 + 2*i]);
    float xi = us2f(src[257 + 2*i]);
    kpe[(size_t)row * 32 + 2*i]     = f2us(xr * c - xi * s);
    kpe[(size_t)row * 32 + 2*i + 1] = f2us(xr * s + xi * c);
  }
}

// ---------------- C2[t] = sinusoid_pe(t/2) @ fc_c_w + b (256-thr partials) -----
__global__ __launch_bounds__(256) void c2_kernel(const float* __restrict__ fccw,
    const float* __restrict__ fccb, float* __restrict__ C2)
{
  const int t = blockIdx.x, tid = threadIdx.x;
  __shared__ float pe[256];
  __shared__ float part[256];
  float p = (float)(t >> 1);
  if (tid < 128){
    float div = __expf((float)(2*tid) * -0.03597789207f);  // -ln(1e4)/256
    float a = p * div;
    pe[2*tid]   = __sinf(a);
    pe[2*tid+1] = __cosf(a);
  }
  __syncthreads();
  {
    int oc = tid & 63, pp = tid >> 6;
    float acc = 0.f;
#pragma unroll 8
    for (int c = pp * 64; c < pp * 64 + 64; ++c)
      acc += pe[c] * fccw[c * 64 + oc];
    part[tid] = acc;
  }
  __syncthreads();
  if (tid < 64)
    C2[t * 64 + tid] = fccb[tid] + part[tid] + part[64 + tid]
                     + part[128 + tid] + part[192 + tid];
}

// ---------------- kv_t: block-diag (DR=2) temporal conv; B_*T_ blocks --------
__global__ __launch_bounds__(64) void kvt_kernel(const float* __restrict__ C2,
    const float* __restrict__ P2, const u16* __restrict__ kvn, u16* __restrict__ kvt)
{
  const int row = blockIdx.x;       // b*T + t
  if (row >= B_ * T_) return;
  const int lane = threadIdx.x;
  const int t = row & (T_ - 1);
  float c2v = C2[t * 64 + lane];
  float da = c2v * P2[(size_t)row * 64 + lane];
  for (int off = 1; off < 64; off <<= 1) da += __shfl_xor(da, off);
  float wtt = 1.f / (1.f + __expf(-da));
  const bool odd = (t & 1);
  float wts = 0.f;
  if (odd){
    float db = c2v * P2[(size_t)(row - 1) * 64 + lane];
    for (int off = 1; off < 64; off <<= 1) db += __shfl_xor(db, off);
    wts = 1.f / (1.f + __expf(-db));
  }
  for (int c = lane; c < 256; c += 64){
    float val = wtt * us2f(kvn[(size_t)row * 256 + c]);
    if (odd) val += wts * us2f(kvn[(size_t)(row - 1) * 256 + c]);
    kvt[(size_t)row * 256 + c] = f2us(val);
  }
}

// ---- fused: Vt transpose-gather (blocks 0..511) + Kc gather (blocks 512..2047) ----
__global__ __launch_bounds__(256) void vtkc_kernel(const u16* __restrict__ kvb,
    const u16* __restrict__ kpe, u16* __restrict__ Vt, u16* __restrict__ Kc)
{
  __shared__ __align__(16) u16 tile[64][72];
  const int tid = threadIdx.x;
  if (blockIdx.x < 512) {
    const int bid = blockIdx.x;
    const int jt = bid & 15;
    const int h  = (bid >> 4) & 15;
    const int b  = bid >> 8;
    const int jl = tid >> 2;
    const int dseg = (tid & 3) * 16;
    const int j0 = jt * 64;
    {
      int s_ = 2 * (j0 + jl) + 1;
      const u16* src = kvb + ((size_t)(b * T_ + s_)) * 2048 + h * 128 + 64 + dseg;
      *(u16x8*)&tile[jl][dseg]     = *(const u16x8*)(src);
      *(u16x8*)&tile[jl][dseg + 8] = *(const u16x8*)(src + 8);
    }
    __syncthreads();
    const int dl = tid >> 2;
    const int jseg = (tid & 3) * 16;
    u16* dst = Vt + ((size_t)(b * 16 + h) * 64 + dl) * 1024 + j0 + jseg;
    u16x8 o;
    for (int r = 0; r < 8; ++r) o[r] = tile[jseg + r][dl];
    *(u16x8*)dst = o;
    for (int r = 0; r < 8; ++r) o[r] = tile[jseg + 8 + r][dl];
    *(u16x8*)(dst + 8) = o;
  } else {
    int idx = (blockIdx.x - 512) * 256 + tid;   // 1536 blocks x 256 chunks
    int c  = idx % 12;
    int j  = (idx / 12) & 1023;
    int bh = idx / (12 * 1024);
    if (bh >= B_ * H_) return;
    int b = bh >> 4, h = bh & 15;
    int t = 2 * j + 1;
    u16x8 v;
    if (c < 8) v = *(const u16x8*)(kvb + ((size_t)(b * T_ + t)) * 2048 + h * 128 + c * 8);
    else       v = *(const u16x8*)(kpe + ((size_t)(b * T_ + t)) * 32 + (c - 8) * 8);
    *(u16x8*)(Kc + ((size_t)bh * 1024 + j) * 96 + c * 8) = v;
  }
}

// ---- flash attention: fixed-max softmax, 128-key LDS chunks, paired q-tiles ----
__global__ __launch_bounds__(256) void attn_kernel(
    const u16* __restrict__ qh, const u16* __restrict__ kvb,
    const u16* __restrict__ kpe, const u16* __restrict__ Kc,
    const u16* __restrict__ Vt, u16* __restrict__ xout)
{
  __shared__ __align__(16) u16 Ks[128 * 96];       // 128 keys x 96 dims, flat
  __shared__ __align__(16) u16 Vs[64][136];        // 64 dims x 128 keys, padded
  __shared__ __align__(16) u16 pbufA[4][16 * 136]; // per-wave P: 16 q x 128 keys
  const int tid  = threadIdx.x;
  const int wid  = tid >> 6;
  const int lane = tid & 63;
  const int quad = lane >> 4;
  const int col  = lane & 15;
  const int pair = blockIdx.x & 15;
  const int h    = (blockIdx.x >> 4) & 15;
  const int b    = blockIdx.x >> 8;
  const int bh   = b * H_ + h;
  u16* pbuf = pbufA[wid];
  const float scale = 0.10206207262f;   // 96^-0.5
  const u16* KcH = Kc + (size_t)bh * 1024 * 96;
  const u16* VtH = Vt + (size_t)bh * 64 * 1024;

  for (int ph = 0; ph < 2; ++ph) {
    const int qt = ph ? (31 - pair) : pair;
    const int t0 = qt * 64 + wid * 16;

    s16x8 aq0, aq1, aq2;
    {
      const u16* qrow = qh + ((size_t)bh * T_ + t0 + col) * 96;
      aq0 = ld8(qrow + quad * 8);
      aq1 = ld8(qrow + 32 + quad * 8);
      aq2 = ld8(qrow + 64 + quad * 8);
    }
    float sself;
    {
      const int t = t0 + col;
      const u16* qrow = qh + ((size_t)bh * T_ + t) * 96;
      const u16* ka = kvb + ((size_t)(b * T_ + t)) * 2048 + h * 128;
      const u16* kp = kpe + ((size_t)(b * T_ + t)) * 32;
      float a = 0.f;
      for (int d = 0; d < 64; ++d) a += us2f(qrow[d]) * us2f(ka[d]);
      for (int d = 0; d < 32; ++d) a += us2f(qrow[64 + d]) * us2f(kp[d]);
      sself = a * scale;
    }
    float es[4], lacc[4];
    f32x4 O[4];
#pragma unroll
    for (int i = 0; i < 4; ++i){
      es[i] = __expf(__shfl(sself, quad * 4 + i));
      lacc[i] = 0.f;
    }
#pragma unroll
    for (int nt = 0; nt < 4; ++nt)
#pragma unroll
      for (int i = 0; i < 4; ++i){
        int t = t0 + quad * 4 + i;
        O[nt][i] = es[i] * us2f(kvb[((size_t)(b * T_ + t)) * 2048 + h * 128 + 64 + nt * 16 + col]);
      }

    const int nb = (qt * 32 + 31 + 127) >> 7;   // 128-key blocks, block-uniform
    for (int blk = 0; blk < nb; ++blk) {
      const int jb = blk * 128;
      __syncthreads();
      {
        const u16* gk = KcH + (size_t)jb * 96 + (size_t)(wid * 6) * 512 + lane * 8;
        u16* lk = &Ks[(wid * 6) * 512];
#pragma unroll
        for (int k = 0; k < 6; ++k)
          gload_lds16(gk + k * 512, lk + k * 512);
        int d = tid >> 2, c4 = tid & 3;
        const u16* gv = VtH + (size_t)d * 1024 + jb + c4 * 32;
        u16* lv = &Vs[d][c4 * 32];
#pragma unroll
        for (int k = 0; k < 4; ++k)
          *(u16x8*)(lv + k * 8) = *(const u16x8*)(gv + k * 8);
      }
      __syncthreads();
#pragma unroll
      for (int cc = 0; cc < 4; ++cc){
        const u16* k0 = &Ks[(cc * 32 + col) * 96];
        const u16* k1 = &Ks[(cc * 32 + 16 + col) * 96];
        f32x4 s0 = {0,0,0,0}, s1 = {0,0,0,0};
        s0 = mfma32(aq0, ld8(k0 + quad * 8), s0);
        s0 = mfma32(aq1, ld8(k0 + 32 + quad * 8), s0);
        s0 = mfma32(aq2, ld8(k0 + 64 + quad * 8), s0);
        s1 = mfma32(aq0, ld8(k1 + quad * 8), s1);
        s1 = mfma32(aq1, ld8(k1 + 32 + quad * 8), s1);
        s1 = mfma32(aq2, ld8(k1 + 64 + quad * 8), s1);
        int key0 = jb + cc * 32 + col;
#pragma unroll
        for (int i = 0; i < 4; ++i){
          int lim = (t0 + quad * 4 + i) >> 1;
          float p0 = (key0 < lim)      ? __expf(s0[i] * scale) : 0.f;
          float p1 = (key0 + 16 < lim) ? __expf(s1[i] * scale) : 0.f;
          lacc[i] += p0 + p1;
          pbuf[(quad * 4 + i) * 136 + cc * 32 + col]      = f2us(p0);
          pbuf[(quad * 4 + i) * 136 + cc * 32 + 16 + col] = f2us(p1);
        }
      }
      asm volatile("s_waitcnt lgkmcnt(0)" ::: "memory");
#pragma unroll
      for (int cc = 0; cc < 4; ++cc){
        s16x8 pf = ld8(&pbuf[col * 136 + cc * 32 + quad * 8]);
#pragma unroll
        for (int nt = 0; nt < 4; ++nt)
          O[nt] = mfma32(pf, ld8(&Vs[nt * 16 + col][cc * 32 + quad * 8]), O[nt]);
      }
    }
#pragma unroll
    for (int i = 0; i < 4; ++i){
      float l = lacc[i];
      l += __shfl_xor(l, 1);
      l += __shfl_xor(l, 2);
      l += __shfl_xor(l, 4);
      l += __shfl_xor(l, 8);
      lacc[i] = es[i] + l;
    }
#pragma unroll
    for (int nt = 0; nt < 4; ++nt)
#pragma unroll
      for (int i = 0; i < 4; ++i){
        int t = t0 + quad * 4 + i;
        xout[((size_t)(b * T_ + t)) * 1024 + h * 64 + nt * 16 + col] = f2us(O[nt][i] / lacc[i]);
      }
    __syncthreads();   // protect Ks/Vs before next phase restages
  }
}

extern "C" void kernel_launch(void* const* d_in, const int* in_sizes, int n_in,
                              void* d_out, int out_size, void* d_ws, size_t ws_size,
                              hipStream_t stream)
{
  (void)in_sizes; (void)n_in; (void)out_size; (void)ws_size;
  const float* query = (const float*)d_in[0];
  const float* key_  = (const float*)d_in[1];
  const int*   pos   = (const int*)d_in[3];
  const float* wq    = (const float*)d_in[4];
  const float* wkva  = (const float*)d_in[5];
  const float* gamma = (const float*)d_in[6];
  const float* beta  = (const float*)d_in[7];
  const float* wkvb  = (const float*)d_in[8];
  const float* wo    = (const float*)d_in[9];
  const float* fccw  = (const float*)d_in[10];
  const float* fccb  = (const float*)d_in[11];
  const float* fcpw  = (const float*)d_in[12];
  const float* fcpb  = (const float*)d_in[13];

  char* p = (char*)d_ws;
  auto alloc = [&](size_t bytes) -> void* {
    void* r = (void*)p;
    p += (bytes + 255) & ~(size_t)255;
    return r;
  };
  u16* wqT    = (u16*)alloc(1536ull * 2048 * 2);
  u16* wkvaT  = (u16*)alloc(288ull  * 2048 * 2);
  u16* woT    = (u16*)alloc(2048ull * 1024 * 2);
  u16* wkvbB  = (u16*)alloc(2048ull * 256 * 2);
  u16* queryB = (u16*)alloc(4096ull * 2048 * 2);
  u16* keyB   = (u16*)alloc(4096ull * 2048 * 2);
  u16* qp0    = (u16*)alloc(4096ull * 1536 * 2);   // split-K partial 0
  u16* qp1    = (u16*)alloc(4096ull * 1536 * 2);   // split-K partial 1
  u16* qh     = (u16*)alloc(65536ull * 96 * 2);    // (B,H,T,96)
  u16* kvall  = (u16*)alloc(4096ull * 288 * 2);
  u16* kvn    = (u16*)alloc(4096ull * 256 * 2);
  u16* kpe    = (u16*)alloc(4096ull * 32 * 2);
  float* P2   = (float*)alloc(4096ull * 64 * 4);
  float* C2   = (float*)alloc(2048ull * 64 * 4);
  u16* kvt    = (u16*)alloc(4096ull * 256 * 2);
  u16* kvb    = (u16*)alloc(4096ull * 2048 * 2);   // per-head [k_abs(64)|v(64)]
  u16* Kc     = (u16*)alloc(32ull * 1024 * 96 * 2);// (B,H,1024,96)
  u16* Vt     = (u16*)alloc(2048ull * 1024 * 2);   // (B,H,64,1024)
  u16* x      = (u16*)alloc(4096ull * 1024 * 2);

  prep_weights<<<6208, 256, 0, stream>>>(wq, wkva, wo, wkvb, wqT, wkvaT, woT, wkvbB);
  cvt2_f32_bf16<<<16384, 256, 0, stream>>>(query, key_, queryB, keyB, 4096 * 2048);

  // q-proj: split-K=2, 768 blocks (3/CU) — fixes round-5 grid starvation (384 blocks, occ 13%)
  gemm128_sk<<<dim3(12, 32, 2), 256, 0, stream>>>(queryB, wqT, qp0, qp1, 4096, 1536, 2048, 1024);
  gemm_bt<0,0><<<dim3(5, 64), 256, 0, stream>>>(keyB, wkvaT, kvall, 4096, 288, 2048);

  qsplit<<<3072, 256, 0, stream>>>(qp0, qp1, pos, qh);
  ln_p2_rope<<<4096, 256, 0, stream>>>(kvall, gamma, beta, fcpw, fcpb, pos, kvn, P2, kpe);
  c2_kernel<<<2048, 256, 0, stream>>>(fccw, fccb, C2);
  kvt_kernel<<<4096, 64, 0, stream>>>(C2, P2, kvn, kvt);

  gemm128<0><<<dim3(16, 32), 256, 0, stream>>>(kvt, wkvbB, kvb, 4096, 2048, 256);
  vtkc_kernel<<<2048, 256, 0, stream>>>(kvb, kpe, Vt, Kc);
  attn_kernel<<<512, 256, 0, stream>>>(qh, kvb, kpe, Kc, Vt, x);

  gemm128<1><<<dim3(16, 32), 256, 0, stream>>>(x, woT, d_out, 4096, 2048, 1024);
}